// Round 1
// baseline (13326.791 us; speedup 1.0000x reference)
//
#include <hip/hip_runtime.h>
#include <cfloat>

#define B_SZ   32768
#define IN_D   1024
#define HID    64
#define COMM   256
#define NPROTO 8192

// ---------------------------------------------------------------------------
// Generic 64x64-tile fp32 GEMM: C[M,N] = act(A[M,Kd] @ W[Kd,N] + bias)
// 256 threads, 4x4 register tile, LDS stride 36 (pad) for bank-conflict relief.
// ACT: 0 = none, 1 = relu
// ---------------------------------------------------------------------------
template<int ACT>
__global__ __launch_bounds__(256) void gemm64(const float* __restrict__ A,
                                              const float* __restrict__ W,
                                              const float* __restrict__ bias,
                                              float* __restrict__ C,
                                              int M, int N, int Kd)
{
    __shared__ float As[64 * 36];
    __shared__ float Ws[64 * 36];
    const int t  = threadIdx.x;
    const int tr = t >> 4;   // 0..15
    const int tc = t & 15;   // 0..15
    const int rowBase = blockIdx.x * 64;
    const int colBase = blockIdx.y * 64;

    float acc[4][4];
#pragma unroll
    for (int u = 0; u < 4; ++u)
#pragma unroll
        for (int v = 0; v < 4; ++v) acc[u][v] = 0.f;

    for (int k0 = 0; k0 < Kd; k0 += 32) {
        __syncthreads();
        // stage A: 64 rows x 32 k = 512 float4, 2 per thread
#pragma unroll
        for (int i = 0; i < 2; ++i) {
            int idx = t + 256 * i;
            int r  = idx >> 3;
            int fj = (idx & 7) << 2;
            float4 v4 = *(const float4*)&A[(size_t)(rowBase + r) * Kd + k0 + fj];
            *(float4*)&As[r * 36 + fj] = v4;
        }
        // stage W transposed: Ws[n][k] <- W[k][n], coalesced along n
#pragma unroll
        for (int i = 0; i < 8; ++i) {
            int idx = t + 256 * i;
            int n  = idx & 63;
            int kk = idx >> 6;
            Ws[n * 36 + kk] = W[(size_t)(k0 + kk) * N + colBase + n];
        }
        __syncthreads();
#pragma unroll
        for (int kk = 0; kk < 32; kk += 4) {
            float4 a[4], b[4];
#pragma unroll
            for (int u = 0; u < 4; ++u) a[u] = *(const float4*)&As[(tr + 16 * u) * 36 + kk];
#pragma unroll
            for (int v = 0; v < 4; ++v) b[v] = *(const float4*)&Ws[(tc + 16 * v) * 36 + kk];
#pragma unroll
            for (int u = 0; u < 4; ++u)
#pragma unroll
                for (int v = 0; v < 4; ++v)
                    acc[u][v] += a[u].x * b[v].x + a[u].y * b[v].y
                               + a[u].z * b[v].z + a[u].w * b[v].w;
        }
    }
#pragma unroll
    for (int v = 0; v < 4; ++v) {
        int n = colBase + tc + 16 * v;
        float bb = bias[n];
#pragma unroll
        for (int u = 0; u < 4; ++u) {
            float c = acc[u][v] + bb;
            if (ACT) c = fmaxf(c, 0.f);
            C[(size_t)(rowBase + tr + 16 * u) * N + n] = c;
        }
    }
}

// ---------------------------------------------------------------------------
// Fused variational head: mu = h3@Wmu+bmu, lv = h3@Wvar+bvar (64x64 tiles),
// sample = mu + eps*exp(0.5*lv); per-block KL partial sum.
// ---------------------------------------------------------------------------
__global__ __launch_bounds__(256) void head_kernel(const float* __restrict__ h3,
                                                   const float* __restrict__ Wmu,
                                                   const float* __restrict__ bmu,
                                                   const float* __restrict__ Wvar,
                                                   const float* __restrict__ bvar,
                                                   const float* __restrict__ eps,
                                                   float* __restrict__ sample,
                                                   float* __restrict__ klpart)
{
    __shared__ float As[64 * 36];
    __shared__ float Wm[64 * 36];
    __shared__ float Wv[64 * 36];
    const int t  = threadIdx.x;
    const int tr = t >> 4;
    const int tc = t & 15;
    const int rowBase = blockIdx.x * 64;
    const int colBase = blockIdx.y * 64;

    float am[4][4], av[4][4];
#pragma unroll
    for (int u = 0; u < 4; ++u)
#pragma unroll
        for (int v = 0; v < 4; ++v) { am[u][v] = 0.f; av[u][v] = 0.f; }

    for (int k0 = 0; k0 < COMM; k0 += 32) {
        __syncthreads();
#pragma unroll
        for (int i = 0; i < 2; ++i) {
            int idx = t + 256 * i;
            int r  = idx >> 3;
            int fj = (idx & 7) << 2;
            float4 v4 = *(const float4*)&h3[(size_t)(rowBase + r) * COMM + k0 + fj];
            *(float4*)&As[r * 36 + fj] = v4;
        }
#pragma unroll
        for (int i = 0; i < 8; ++i) {
            int idx = t + 256 * i;
            int n  = idx & 63;
            int kk = idx >> 6;
            Wm[n * 36 + kk] = Wmu [(size_t)(k0 + kk) * COMM + colBase + n];
            Wv[n * 36 + kk] = Wvar[(size_t)(k0 + kk) * COMM + colBase + n];
        }
        __syncthreads();
#pragma unroll
        for (int kk = 0; kk < 32; kk += 4) {
            float4 a[4], bm[4], bv4[4];
#pragma unroll
            for (int u = 0; u < 4; ++u) a[u]   = *(const float4*)&As[(tr + 16 * u) * 36 + kk];
#pragma unroll
            for (int v = 0; v < 4; ++v) bm[v]  = *(const float4*)&Wm[(tc + 16 * v) * 36 + kk];
#pragma unroll
            for (int v = 0; v < 4; ++v) bv4[v] = *(const float4*)&Wv[(tc + 16 * v) * 36 + kk];
#pragma unroll
            for (int u = 0; u < 4; ++u)
#pragma unroll
                for (int v = 0; v < 4; ++v) {
                    am[u][v] += a[u].x * bm[v].x + a[u].y * bm[v].y
                              + a[u].z * bm[v].z + a[u].w * bm[v].w;
                    av[u][v] += a[u].x * bv4[v].x + a[u].y * bv4[v].y
                              + a[u].z * bv4[v].z + a[u].w * bv4[v].w;
                }
        }
    }
    float kl = 0.f;
#pragma unroll
    for (int v = 0; v < 4; ++v) {
        int n = colBase + tc + 16 * v;
        float bmu_n  = bmu[n];
        float bvar_n = bvar[n];
#pragma unroll
        for (int u = 0; u < 4; ++u) {
            int row = rowBase + tr + 16 * u;
            float mu = am[u][v] + bmu_n;
            float lv = av[u][v] + bvar_n;
            float e  = expf(0.5f * lv);              // exp(lv) = e*e
            float s  = mu + eps[(size_t)row * COMM + n] * e;
            sample[(size_t)row * COMM + n] = s;
            kl += 1.f + lv - mu * mu - e * e;
        }
    }
    // block-reduce kl
#pragma unroll
    for (int off = 32; off; off >>= 1) kl += __shfl_down(kl, off);
    __shared__ float wsum[4];
    if ((t & 63) == 0) wsum[t >> 6] = kl;
    __syncthreads();
    if (t == 0)
        klpart[blockIdx.y * gridDim.x + blockIdx.x] = wsum[0] + wsum[1] + wsum[2] + wsum[3];
}

// ---------------------------------------------------------------------------
// pnorm[k] = sum_j protos[k][j]^2  (one wave per proto)
// ---------------------------------------------------------------------------
__global__ __launch_bounds__(256) void pnorm_kernel(const float* __restrict__ protos,
                                                    float* __restrict__ pnorm)
{
    int g    = blockIdx.x * 256 + threadIdx.x;
    int wave = g >> 6;
    int lane = g & 63;
    float4 v = *(const float4*)&protos[(size_t)wave * COMM + lane * 4];
    float s = v.x * v.x + v.y * v.y + v.z * v.z + v.w * v.w;
#pragma unroll
    for (int off = 32; off; off >>= 1) s += __shfl_down(s, off);
    if (lane == 0) pnorm[wave] = s;
}

// ---------------------------------------------------------------------------
// Distance + argmin: score[i][k] = pnorm[k] - 2*dot(sample_i, proto_k)
// (the row-constant ||s||^2 does not affect argmin).
// 128 rows x 128 protos per tile, 8x8 register tile, 4-way proto split.
// ---------------------------------------------------------------------------
__global__ __launch_bounds__(256) void vq_argmin(const float* __restrict__ sample,
                                                 const float* __restrict__ protos,
                                                 const float* __restrict__ pnorm,
                                                 float* __restrict__ minval,
                                                 int* __restrict__ minidx)
{
    __shared__ float As[128 * 36];
    __shared__ float Bs[128 * 36];
    const int t  = threadIdx.x;
    const int tr = t >> 4;   // 0..15
    const int tc = t & 15;   // 0..15
    const int rowBase = blockIdx.x * 128;
    const int pBase   = blockIdx.y * (NPROTO / 4);

    float bestv[8];
    int   besti[8];
#pragma unroll
    for (int u = 0; u < 8; ++u) { bestv[u] = FLT_MAX; besti[u] = 0; }

    for (int p0 = pBase; p0 < pBase + NPROTO / 4; p0 += 128) {
        float acc[8][8];
#pragma unroll
        for (int u = 0; u < 8; ++u)
#pragma unroll
            for (int v = 0; v < 8; ++v) acc[u][v] = 0.f;

        for (int k0 = 0; k0 < COMM; k0 += 32) {
            __syncthreads();
            // stage 128x32 of sample and protos (1024 float4 each, 4/thread each)
#pragma unroll
            for (int i = 0; i < 4; ++i) {
                int idx = t + 256 * i;
                int r  = idx >> 3;
                int fj = (idx & 7) << 2;
                *(float4*)&As[r * 36 + fj] =
                    *(const float4*)&sample[(size_t)(rowBase + r) * COMM + k0 + fj];
                *(float4*)&Bs[r * 36 + fj] =
                    *(const float4*)&protos[(size_t)(p0 + r) * COMM + k0 + fj];
            }
            __syncthreads();
#pragma unroll
            for (int kk = 0; kk < 32; kk += 4) {
                float4 a[8], b[8];
#pragma unroll
                for (int u = 0; u < 8; ++u) a[u] = *(const float4*)&As[(tr + 16 * u) * 36 + kk];
#pragma unroll
                for (int v = 0; v < 8; ++v) b[v] = *(const float4*)&Bs[(tc + 16 * v) * 36 + kk];
#pragma unroll
                for (int u = 0; u < 8; ++u)
#pragma unroll
                    for (int v = 0; v < 8; ++v)
                        acc[u][v] += a[u].x * b[v].x + a[u].y * b[v].y
                                   + a[u].z * b[v].z + a[u].w * b[v].w;
            }
        }
        // epilogue: running min (p ascending per thread -> strict < keeps first)
#pragma unroll
        for (int v = 0; v < 8; ++v) {
            int p = p0 + tc + 16 * v;
            float pn = pnorm[p];
#pragma unroll
            for (int u = 0; u < 8; ++u) {
                float score = pn - 2.f * acc[u][v];
                if (score < bestv[u]) { bestv[u] = score; besti[u] = p; }
            }
        }
    }
    // cross-thread (tc) reduce via LDS scratch
    __syncthreads();
#pragma unroll
    for (int u = 0; u < 8; ++u) {
        As[(tr + 16 * u) * 16 + tc] = bestv[u];
        ((int*)Bs)[(tr + 16 * u) * 16 + tc] = besti[u];
    }
    __syncthreads();
    if (t < 128) {
        float bv = FLT_MAX; int bi = 0x7fffffff;
#pragma unroll
        for (int j = 0; j < 16; ++j) {
            float v = As[t * 16 + j];
            int  pi = ((int*)Bs)[t * 16 + j];
            if (v < bv || (v == bv && pi < bi)) { bv = v; bi = pi; }
        }
        minval[(size_t)blockIdx.y * B_SZ + rowBase + t] = bv;
        minidx[(size_t)blockIdx.y * B_SZ + rowBase + t] = bi;
    }
}

// ---------------------------------------------------------------------------
// Combine the 4 proto-split candidates per row (tie-break: smallest index)
// ---------------------------------------------------------------------------
__global__ __launch_bounds__(256) void combine_kernel(const float* __restrict__ minval,
                                                      const int* __restrict__ minidx,
                                                      int* __restrict__ idx)
{
    int i = blockIdx.x * 256 + threadIdx.x;
    float bv = minval[i];
    int   bi = minidx[i];
#pragma unroll
    for (int s = 1; s < 4; ++s) {
        float v = minval[(size_t)s * B_SZ + i];
        int   j = minidx[(size_t)s * B_SZ + i];
        if (v < bv || (v == bv && j < bi)) { bv = v; bi = j; }
    }
    idx[i] = bi;
}

// ---------------------------------------------------------------------------
// Gather q = protos[idx], write q_st = sample + (q - sample) (faithful
// straight-through rounding), per-block MSE partials. 8 rows per block.
// ---------------------------------------------------------------------------
__global__ __launch_bounds__(256) void gather_kernel(const float* __restrict__ sample,
                                                     const float* __restrict__ protos,
                                                     const int* __restrict__ idx,
                                                     float* __restrict__ out,
                                                     float* __restrict__ msepart)
{
    int t  = threadIdx.x;          // dim 0..255
    int rb = blockIdx.x * 8;
    float part = 0.f;
#pragma unroll
    for (int u = 0; u < 8; ++u) {
        int i  = rb + u;
        int id = idx[i];
        float q = protos[(size_t)id * COMM + t];
        float s = sample[(size_t)i * COMM + t];
        float d = q - s;
        out[(size_t)i * COMM + t] = s + d;
        part += d * d;
    }
#pragma unroll
    for (int off = 32; off; off >>= 1) part += __shfl_down(part, off);
    __shared__ float wsum[4];
    if ((t & 63) == 0) wsum[t >> 6] = part;
    __syncthreads();
    if (t == 0) msepart[blockIdx.x] = wsum[0] + wsum[1] + wsum[2] + wsum[3];
}

// ---------------------------------------------------------------------------
// Final scalars: out[B*COMM] = total_loss, out[B*COMM+1] = kld
// ---------------------------------------------------------------------------
__global__ __launch_bounds__(256) void finalize_kernel(const float* __restrict__ klpart, int nkl,
                                                       const float* __restrict__ msepart, int nmse,
                                                       float* __restrict__ out)
{
    int t = threadIdx.x;
    double kl = 0.0, mse = 0.0;
    for (int i = t; i < nkl;  i += 256) kl  += (double)klpart[i];
    for (int i = t; i < nmse; i += 256) mse += (double)msepart[i];
#pragma unroll
    for (int off = 32; off; off >>= 1) {
        kl  += __shfl_down(kl, off);
        mse += __shfl_down(mse, off);
    }
    __shared__ double skl[4], smse[4];
    if ((t & 63) == 0) { skl[t >> 6] = kl; smse[t >> 6] = mse; }
    __syncthreads();
    if (t == 0) {
        double K  = skl[0] + skl[1] + skl[2] + skl[3];
        double M  = smse[0] + smse[1] + smse[2] + smse[3];
        double kld = -0.5 * K / (double)B_SZ;
        double vq  = 1.25 * M / ((double)B_SZ * (double)COMM);  // beta*commit + embed
        out[(size_t)B_SZ * COMM]     = (float)(kld + vq);
        out[(size_t)B_SZ * COMM + 1] = (float)kld;
    }
}

// ---------------------------------------------------------------------------
extern "C" void kernel_launch(void* const* d_in, const int* in_sizes, int n_in,
                              void* d_out, int out_size, void* d_ws, size_t ws_size,
                              hipStream_t stream)
{
    const float* x      = (const float*)d_in[0];
    const float* eps    = (const float*)d_in[1];
    const float* W_feat = (const float*)d_in[2];
    const float* b_feat = (const float*)d_in[3];
    const float* W0     = (const float*)d_in[4];
    const float* b0     = (const float*)d_in[5];
    const float* W1     = (const float*)d_in[6];
    const float* b1     = (const float*)d_in[7];
    const float* W_mu   = (const float*)d_in[8];
    const float* b_mu   = (const float*)d_in[9];
    const float* W_var  = (const float*)d_in[10];
    const float* b_var  = (const float*)d_in[11];
    const float* protos = (const float*)d_in[12];
    float* out = (float*)d_out;

    char* wsb = (char*)d_ws;
    size_t off = 0;
    auto alloc = [&](size_t bytes) -> void* {
        void* p = wsb + off;
        off = (off + bytes + 255) & ~(size_t)255;
        return p;
    };
    float* h1      = (float*)alloc((size_t)B_SZ * HID  * 4);
    float* h2      = (float*)alloc((size_t)B_SZ * HID  * 4);
    float* h3      = (float*)alloc((size_t)B_SZ * COMM * 4);
    float* sample  = (float*)alloc((size_t)B_SZ * COMM * 4);
    float* pnorm   = (float*)alloc((size_t)NPROTO * 4);
    float* minval  = (float*)alloc(4 * (size_t)B_SZ * 4);
    int*   minidx  = (int*)  alloc(4 * (size_t)B_SZ * 4);
    int*   idx     = (int*)  alloc((size_t)B_SZ * 4);
    float* klpart  = (float*)alloc(2048 * 4);
    float* msepart = (float*)alloc(4096 * 4);

    // MLP
    gemm64<0><<<dim3(512, 1), 256, 0, stream>>>(x,  W_feat, b_feat, h1, B_SZ, HID,  IN_D);
    gemm64<1><<<dim3(512, 1), 256, 0, stream>>>(h1, W0,     b0,     h2, B_SZ, HID,  HID);
    gemm64<1><<<dim3(512, 4), 256, 0, stream>>>(h2, W1,     b1,     h3, B_SZ, COMM, HID);
    // variational head (fused mu/logvar/sample/KL-partials)
    head_kernel<<<dim3(512, 4), 256, 0, stream>>>(h3, W_mu, b_mu, W_var, b_var, eps,
                                                  sample, klpart);
    // VQ
    pnorm_kernel<<<NPROTO / 4, 256, 0, stream>>>(protos, pnorm);
    vq_argmin<<<dim3(B_SZ / 128, 4), 256, 0, stream>>>(sample, protos, pnorm, minval, minidx);
    combine_kernel<<<B_SZ / 256, 256, 0, stream>>>(minval, minidx, idx);
    gather_kernel<<<B_SZ / 8, 256, 0, stream>>>(sample, protos, idx, out, msepart);
    finalize_kernel<<<1, 256, 0, stream>>>(klpart, 2048, msepart, 4096, out);
}

// Round 2
// 979.898 us; speedup vs baseline: 13.6002x; 13.6002x over previous
//
#include <hip/hip_runtime.h>
#include <cfloat>

#define B_SZ   32768
#define IN_D   1024
#define HID    64
#define COMM   256
#define NPROTO 8192

typedef __attribute__((ext_vector_type(8))) short bf16x8;
typedef __attribute__((ext_vector_type(4))) float f32x4;

__device__ __forceinline__ unsigned short f2bf(float f) {
    unsigned u = __float_as_uint(f);
    unsigned r = u + 0x7fff + ((u >> 16) & 1);   // round-to-nearest-even
    return (unsigned short)(r >> 16);
}

// ---------------------------------------------------------------------------
// Generic 64x64-tile fp32 GEMM: C[M,N] = act(A[M,Kd] @ W[Kd,N] + bias)
// ---------------------------------------------------------------------------
template<int ACT>
__global__ __launch_bounds__(256) void gemm64(const float* __restrict__ A,
                                              const float* __restrict__ W,
                                              const float* __restrict__ bias,
                                              float* __restrict__ C,
                                              int M, int N, int Kd)
{
    __shared__ float As[64 * 36];
    __shared__ float Ws[64 * 36];
    const int t  = threadIdx.x;
    const int tr = t >> 4;
    const int tc = t & 15;
    const int rowBase = blockIdx.x * 64;
    const int colBase = blockIdx.y * 64;

    float acc[4][4];
#pragma unroll
    for (int u = 0; u < 4; ++u)
#pragma unroll
        for (int v = 0; v < 4; ++v) acc[u][v] = 0.f;

    for (int k0 = 0; k0 < Kd; k0 += 32) {
        __syncthreads();
#pragma unroll
        for (int i = 0; i < 2; ++i) {
            int idx = t + 256 * i;
            int r  = idx >> 3;
            int fj = (idx & 7) << 2;
            float4 v4 = *(const float4*)&A[(size_t)(rowBase + r) * Kd + k0 + fj];
            *(float4*)&As[r * 36 + fj] = v4;
        }
#pragma unroll
        for (int i = 0; i < 8; ++i) {
            int idx = t + 256 * i;
            int n  = idx & 63;
            int kk = idx >> 6;
            Ws[n * 36 + kk] = W[(size_t)(k0 + kk) * N + colBase + n];
        }
        __syncthreads();
#pragma unroll
        for (int kk = 0; kk < 32; kk += 4) {
            float4 a[4], b[4];
#pragma unroll
            for (int u = 0; u < 4; ++u) a[u] = *(const float4*)&As[(tr + 16 * u) * 36 + kk];
#pragma unroll
            for (int v = 0; v < 4; ++v) b[v] = *(const float4*)&Ws[(tc + 16 * v) * 36 + kk];
#pragma unroll
            for (int u = 0; u < 4; ++u)
#pragma unroll
                for (int v = 0; v < 4; ++v)
                    acc[u][v] += a[u].x * b[v].x + a[u].y * b[v].y
                               + a[u].z * b[v].z + a[u].w * b[v].w;
        }
    }
#pragma unroll
    for (int v = 0; v < 4; ++v) {
        int n = colBase + tc + 16 * v;
        float bb = bias[n];
#pragma unroll
        for (int u = 0; u < 4; ++u) {
            float c = acc[u][v] + bb;
            if (ACT) c = fmaxf(c, 0.f);
            C[(size_t)(rowBase + tr + 16 * u) * N + n] = c;
        }
    }
}

// ---------------------------------------------------------------------------
// Fused variational head: mu/logvar GEMMs + reparameterize + KL partials.
// Also emits bf16 copy of sample for the MFMA distance kernel.
// ---------------------------------------------------------------------------
__global__ __launch_bounds__(256) void head_kernel(const float* __restrict__ h3,
                                                   const float* __restrict__ Wmu,
                                                   const float* __restrict__ bmu,
                                                   const float* __restrict__ Wvar,
                                                   const float* __restrict__ bvar,
                                                   const float* __restrict__ eps,
                                                   float* __restrict__ sample,
                                                   unsigned short* __restrict__ sampleb,
                                                   float* __restrict__ klpart)
{
    __shared__ float As[64 * 36];
    __shared__ float Wm[64 * 36];
    __shared__ float Wv[64 * 36];
    const int t  = threadIdx.x;
    const int tr = t >> 4;
    const int tc = t & 15;
    const int rowBase = blockIdx.x * 64;
    const int colBase = blockIdx.y * 64;

    float am[4][4], av[4][4];
#pragma unroll
    for (int u = 0; u < 4; ++u)
#pragma unroll
        for (int v = 0; v < 4; ++v) { am[u][v] = 0.f; av[u][v] = 0.f; }

    for (int k0 = 0; k0 < COMM; k0 += 32) {
        __syncthreads();
#pragma unroll
        for (int i = 0; i < 2; ++i) {
            int idx = t + 256 * i;
            int r  = idx >> 3;
            int fj = (idx & 7) << 2;
            float4 v4 = *(const float4*)&h3[(size_t)(rowBase + r) * COMM + k0 + fj];
            *(float4*)&As[r * 36 + fj] = v4;
        }
#pragma unroll
        for (int i = 0; i < 8; ++i) {
            int idx = t + 256 * i;
            int n  = idx & 63;
            int kk = idx >> 6;
            Wm[n * 36 + kk] = Wmu [(size_t)(k0 + kk) * COMM + colBase + n];
            Wv[n * 36 + kk] = Wvar[(size_t)(k0 + kk) * COMM + colBase + n];
        }
        __syncthreads();
#pragma unroll
        for (int kk = 0; kk < 32; kk += 4) {
            float4 a[4], bm[4], bv4[4];
#pragma unroll
            for (int u = 0; u < 4; ++u) a[u]   = *(const float4*)&As[(tr + 16 * u) * 36 + kk];
#pragma unroll
            for (int v = 0; v < 4; ++v) bm[v]  = *(const float4*)&Wm[(tc + 16 * v) * 36 + kk];
#pragma unroll
            for (int v = 0; v < 4; ++v) bv4[v] = *(const float4*)&Wv[(tc + 16 * v) * 36 + kk];
#pragma unroll
            for (int u = 0; u < 4; ++u)
#pragma unroll
                for (int v = 0; v < 4; ++v) {
                    am[u][v] += a[u].x * bm[v].x + a[u].y * bm[v].y
                              + a[u].z * bm[v].z + a[u].w * bm[v].w;
                    av[u][v] += a[u].x * bv4[v].x + a[u].y * bv4[v].y
                              + a[u].z * bv4[v].z + a[u].w * bv4[v].w;
                }
        }
    }
    float kl = 0.f;
#pragma unroll
    for (int v = 0; v < 4; ++v) {
        int n = colBase + tc + 16 * v;
        float bmu_n  = bmu[n];
        float bvar_n = bvar[n];
#pragma unroll
        for (int u = 0; u < 4; ++u) {
            int row = rowBase + tr + 16 * u;
            float mu = am[u][v] + bmu_n;
            float lv = av[u][v] + bvar_n;
            float e  = expf(0.5f * lv);
            float s  = mu + eps[(size_t)row * COMM + n] * e;
            sample [(size_t)row * COMM + n] = s;
            sampleb[(size_t)row * COMM + n] = f2bf(s);
            kl += 1.f + lv - mu * mu - e * e;
        }
    }
#pragma unroll
    for (int off = 32; off; off >>= 1) kl += __shfl_down(kl, off);
    __shared__ float wsum[4];
    if ((t & 63) == 0) wsum[t >> 6] = kl;
    __syncthreads();
    if (t == 0)
        klpart[blockIdx.y * gridDim.x + blockIdx.x] = wsum[0] + wsum[1] + wsum[2] + wsum[3];
}

// ---------------------------------------------------------------------------
// pnorm[k] = ||protos[k]||^2 (fp32) and bf16 conversion of protos.
// ---------------------------------------------------------------------------
__global__ __launch_bounds__(256) void pnorm_conv_kernel(const float* __restrict__ protos,
                                                         float* __restrict__ pnorm,
                                                         unsigned short* __restrict__ protosb)
{
    int g    = blockIdx.x * 256 + threadIdx.x;
    int wave = g >> 6;
    int lane = g & 63;
    float4 v = *(const float4*)&protos[(size_t)wave * COMM + lane * 4];
    ushort4 b;
    b.x = f2bf(v.x); b.y = f2bf(v.y); b.z = f2bf(v.z); b.w = f2bf(v.w);
    *(ushort4*)&protosb[(size_t)wave * COMM + lane * 4] = b;
    float s = v.x * v.x + v.y * v.y + v.z * v.z + v.w * v.w;
#pragma unroll
    for (int off = 32; off; off >>= 1) s += __shfl_down(s, off);
    if (lane == 0) pnorm[wave] = s;
}

// ---------------------------------------------------------------------------
// MFMA distance + argmin.
// score[i][k] = pnorm[k] - 2*dot(sample_i, proto_k)  (||s||^2 dropped).
// Block: 256 thr (4 waves, 2x2 over a 128-row x 128-proto tile).
// A (128 rows x K=256 bf16, 64 KB) resident in LDS for all 16 proto tiles;
// B staged per 64-k slice (16 KB) via global_load_lds(16B).
// XOR-swizzled 16B-chunk layout keeps ds_read_b128 at <=2-way bank aliasing.
// ---------------------------------------------------------------------------
#define SPLITS 4
#define SPAN   (NPROTO / SPLITS)   // 2048
#define NT     (SPAN / 128)        // 16 proto tiles per block

__global__ __launch_bounds__(256) void vq_argmin_mfma(
    const unsigned short* __restrict__ sampleb,
    const unsigned short* __restrict__ protosb,
    const float* __restrict__ pnorm,
    float* __restrict__ minval,
    int* __restrict__ minidx)
{
    __shared__ __align__(16) short As[128 * 256];  // 64 KB
    __shared__ __align__(16) short Bs[128 * 64];   // 16 KB

    const int t   = threadIdx.x;
    const int w   = t >> 6;        // wave 0..3
    const int l   = t & 63;
    const int q   = l >> 4;        // quad 0..3
    const int j16 = l & 15;
    const int wrow = (w >> 1) * 64;
    const int wcol = (w & 1) * 64;
    const int rowBase = blockIdx.x * 128;
    const int pBase   = blockIdx.y * SPAN;

    // ---- stage A: 4096 16B chunks, swizzled: chunk(r, js) holds row r,
    //      k-chunk j = (js&24) | ((js&7) ^ (r&7))
#pragma unroll
    for (int i = 0; i < 16; ++i) {
        int p  = i * 256 + t;
        int r  = p >> 5;
        int js = p & 31;
        int j  = (js & 24) | ((js & 7) ^ (r & 7));
        const unsigned short* g = sampleb + (size_t)(rowBase + r) * COMM + j * 8;
        void* lds = (char*)As + (size_t)(i * 256 + w * 64) * 16;
        __builtin_amdgcn_global_load_lds(
            (const __attribute__((address_space(1))) void*)g,
            (__attribute__((address_space(3))) void*)lds, 16, 0, 0);
    }

    float bestv[16];
    int   besti[16];
#pragma unroll
    for (int s = 0; s < 16; ++s) { bestv[s] = FLT_MAX; besti[s] = 0; }

    for (int pt = 0; pt < NT; ++pt) {
        const int pTile = pBase + pt * 128;
        f32x4 acc[4][4];
#pragma unroll
        for (int u = 0; u < 4; ++u)
#pragma unroll
            for (int v = 0; v < 4; ++v) acc[u][v] = (f32x4){0.f, 0.f, 0.f, 0.f};

        for (int ks = 0; ks < 4; ++ks) {
            __syncthreads();   // protect Bs (and, first pass, drain A staging)
#pragma unroll
            for (int i = 0; i < 4; ++i) {
                int p  = i * 256 + t;
                int r  = p >> 3;
                int js = p & 7;
                int j  = js ^ (r & 7);
                const unsigned short* g =
                    protosb + (size_t)(pTile + r) * COMM + ks * 64 + j * 8;
                void* lds = (char*)Bs + (size_t)(i * 256 + w * 64) * 16;
                __builtin_amdgcn_global_load_lds(
                    (const __attribute__((address_space(1))) void*)g,
                    (__attribute__((address_space(3))) void*)lds, 16, 0, 0);
            }
            __syncthreads();
#pragma unroll
            for (int s = 0; s < 2; ++s) {
                const int kk = ks * 2 + s;
                bf16x8 af[4], bfv[4];
#pragma unroll
                for (int u = 0; u < 4; ++u) {
                    int m   = wrow + 16 * u + j16;
                    int jw  = kk * 4 + q;
                    int pos = m * 32 + ((jw & 24) | ((jw & 7) ^ (m & 7)));
                    af[u] = *(const bf16x8*)((const char*)As + (size_t)pos * 16);
                }
#pragma unroll
                for (int v = 0; v < 4; ++v) {
                    int n   = wcol + 16 * v + j16;
                    int jw  = s * 4 + q;
                    int pos = n * 8 + (jw ^ (n & 7));
                    bfv[v] = *(const bf16x8*)((const char*)Bs + (size_t)pos * 16);
                }
#pragma unroll
                for (int u = 0; u < 4; ++u)
#pragma unroll
                    for (int v = 0; v < 4; ++v)
                        acc[u][v] = __builtin_amdgcn_mfma_f32_16x16x32_bf16(
                            af[u], bfv[v], acc[u][v], 0, 0, 0);
            }
        }
        // epilogue: running argmin. C/D layout: col=lane&15, row=quad*4+reg.
#pragma unroll
        for (int v = 0; v < 4; ++v) {
            int col  = pTile + wcol + 16 * v + j16;
            float pn = pnorm[col];
#pragma unroll
            for (int u = 0; u < 4; ++u)
#pragma unroll
                for (int rg = 0; rg < 4; ++rg) {
                    float sc   = pn - 2.f * acc[u][v][rg];
                    int   slot = u * 4 + rg;
                    if (sc < bestv[slot]) { bestv[slot] = sc; besti[slot] = col; }
                }
        }
    }
    // reduce over the 16 lanes of each quad-group (they share rows)
#pragma unroll
    for (int off = 1; off < 16; off <<= 1) {
#pragma unroll
        for (int s = 0; s < 16; ++s) {
            float ov = __shfl_xor(bestv[s], off);
            int   oi = __shfl_xor(besti[s], off);
            if (ov < bestv[s] || (ov == bestv[s] && oi < besti[s])) {
                bestv[s] = ov; besti[s] = oi;
            }
        }
    }
    // cross-wave (col halves) via LDS reuse of Bs
    __syncthreads();
    float* cv = (float*)Bs;
    int*   ci = ((int*)Bs) + 256;
    if (j16 == 0) {
#pragma unroll
        for (int u = 0; u < 4; ++u)
#pragma unroll
            for (int rg = 0; rg < 4; ++rg) {
                int row = wrow + 16 * u + 4 * q + rg;
                cv[(w & 1) * 128 + row] = bestv[u * 4 + rg];
                ci[(w & 1) * 128 + row] = besti[u * 4 + rg];
            }
    }
    __syncthreads();
    if (t < 128) {
        float v0 = cv[t];       int i0 = ci[t];
        float v1 = cv[128 + t]; int i1 = ci[128 + t];
        if (v1 < v0 || (v1 == v0 && i1 < i0)) { v0 = v1; i0 = i1; }
        minval[(size_t)blockIdx.y * B_SZ + rowBase + t] = v0;
        minidx[(size_t)blockIdx.y * B_SZ + rowBase + t] = i0;
    }
}

// ---------------------------------------------------------------------------
__global__ __launch_bounds__(256) void combine_kernel(const float* __restrict__ minval,
                                                      const int* __restrict__ minidx,
                                                      int* __restrict__ idx)
{
    int i = blockIdx.x * 256 + threadIdx.x;
    float bv = minval[i];
    int   bi = minidx[i];
#pragma unroll
    for (int s = 1; s < SPLITS; ++s) {
        float v = minval[(size_t)s * B_SZ + i];
        int   j = minidx[(size_t)s * B_SZ + i];
        if (v < bv || (v == bv && j < bi)) { bv = v; bi = j; }
    }
    idx[i] = bi;
}

// ---------------------------------------------------------------------------
__global__ __launch_bounds__(256) void gather_kernel(const float* __restrict__ sample,
                                                     const float* __restrict__ protos,
                                                     const int* __restrict__ idx,
                                                     float* __restrict__ out,
                                                     float* __restrict__ msepart)
{
    int t  = threadIdx.x;
    int rb = blockIdx.x * 8;
    float part = 0.f;
#pragma unroll
    for (int u = 0; u < 8; ++u) {
        int i  = rb + u;
        int id = idx[i];
        float qv = protos[(size_t)id * COMM + t];
        float s  = sample[(size_t)i * COMM + t];
        float d  = qv - s;
        out[(size_t)i * COMM + t] = s + d;
        part += d * d;
    }
#pragma unroll
    for (int off = 32; off; off >>= 1) part += __shfl_down(part, off);
    __shared__ float wsum[4];
    if ((t & 63) == 0) wsum[t >> 6] = part;
    __syncthreads();
    if (t == 0) msepart[blockIdx.x] = wsum[0] + wsum[1] + wsum[2] + wsum[3];
}

// ---------------------------------------------------------------------------
__global__ __launch_bounds__(256) void finalize_kernel(const float* __restrict__ klpart, int nkl,
                                                       const float* __restrict__ msepart, int nmse,
                                                       float* __restrict__ out)
{
    int t = threadIdx.x;
    double kl = 0.0, mse = 0.0;
    for (int i = t; i < nkl;  i += 256) kl  += (double)klpart[i];
    for (int i = t; i < nmse; i += 256) mse += (double)msepart[i];
#pragma unroll
    for (int off = 32; off; off >>= 1) {
        kl  += __shfl_down(kl, off);
        mse += __shfl_down(mse, off);
    }
    __shared__ double skl[4], smse[4];
    if ((t & 63) == 0) { skl[t >> 6] = kl; smse[t >> 6] = mse; }
    __syncthreads();
    if (t == 0) {
        double K  = skl[0] + skl[1] + skl[2] + skl[3];
        double M  = smse[0] + smse[1] + smse[2] + smse[3];
        double kld = -0.5 * K / (double)B_SZ;
        double vq  = 1.25 * M / ((double)B_SZ * (double)COMM);
        out[(size_t)B_SZ * COMM]     = (float)(kld + vq);
        out[(size_t)B_SZ * COMM + 1] = (float)kld;
    }
}

// ---------------------------------------------------------------------------
extern "C" void kernel_launch(void* const* d_in, const int* in_sizes, int n_in,
                              void* d_out, int out_size, void* d_ws, size_t ws_size,
                              hipStream_t stream)
{
    const float* x      = (const float*)d_in[0];
    const float* eps    = (const float*)d_in[1];
    const float* W_feat = (const float*)d_in[2];
    const float* b_feat = (const float*)d_in[3];
    const float* W0     = (const float*)d_in[4];
    const float* b0     = (const float*)d_in[5];
    const float* W1     = (const float*)d_in[6];
    const float* b1     = (const float*)d_in[7];
    const float* W_mu   = (const float*)d_in[8];
    const float* b_mu   = (const float*)d_in[9];
    const float* W_var  = (const float*)d_in[10];
    const float* b_var  = (const float*)d_in[11];
    const float* protos = (const float*)d_in[12];
    float* out = (float*)d_out;

    char* wsb = (char*)d_ws;
    size_t off = 0;
    auto alloc = [&](size_t bytes) -> void* {
        void* p = wsb + off;
        off = (off + bytes + 255) & ~(size_t)255;
        return p;
    };
    float*          h1      = (float*)alloc((size_t)B_SZ * HID  * 4);
    float*          h2      = (float*)alloc((size_t)B_SZ * HID  * 4);
    float*          h3      = (float*)alloc((size_t)B_SZ * COMM * 4);
    float*          sample  = (float*)alloc((size_t)B_SZ * COMM * 4);
    unsigned short* sampleb = (unsigned short*)alloc((size_t)B_SZ * COMM * 2);
    unsigned short* protosb = (unsigned short*)alloc((size_t)NPROTO * COMM * 2);
    float*          pnorm   = (float*)alloc((size_t)NPROTO * 4);
    float*          minval  = (float*)alloc((size_t)SPLITS * B_SZ * 4);
    int*            minidx  = (int*)  alloc((size_t)SPLITS * B_SZ * 4);
    int*            idx     = (int*)  alloc((size_t)B_SZ * 4);
    float*          klpart  = (float*)alloc(2048 * 4);
    float*          msepart = (float*)alloc(4096 * 4);

    // MLP (fp32, exact)
    gemm64<0><<<dim3(512, 1), 256, 0, stream>>>(x,  W_feat, b_feat, h1, B_SZ, HID,  IN_D);
    gemm64<1><<<dim3(512, 1), 256, 0, stream>>>(h1, W0,     b0,     h2, B_SZ, HID,  HID);
    gemm64<1><<<dim3(512, 4), 256, 0, stream>>>(h2, W1,     b1,     h3, B_SZ, COMM, HID);
    // variational head (fp32 exact; also emits bf16 sample)
    head_kernel<<<dim3(512, 4), 256, 0, stream>>>(h3, W_mu, b_mu, W_var, b_var, eps,
                                                  sample, sampleb, klpart);
    // VQ scoring in bf16 MFMA
    pnorm_conv_kernel<<<NPROTO / 4, 256, 0, stream>>>(protos, pnorm, protosb);
    vq_argmin_mfma<<<dim3(B_SZ / 128, SPLITS), 256, 0, stream>>>(sampleb, protosb, pnorm,
                                                                 minval, minidx);
    combine_kernel<<<B_SZ / 256, 256, 0, stream>>>(minval, minidx, idx);
    // exact fp32 epilogue
    gather_kernel<<<B_SZ / 8, 256, 0, stream>>>(sample, protos, idx, out, msepart);
    finalize_kernel<<<1, 256, 0, stream>>>(klpart, 2048, msepart, 4096, out);
}

// Round 3
// 469.469 us; speedup vs baseline: 28.3870x; 2.0872x over previous
//
#include <hip/hip_runtime.h>
#include <cfloat>

#define B_SZ   32768
#define IN_D   1024
#define HID    64
#define COMM   256
#define NPROTO 8192

typedef __attribute__((ext_vector_type(8))) short bf16x8;
typedef __attribute__((ext_vector_type(4))) float f32x4;

__device__ __forceinline__ unsigned short f2bf(float f) {
    unsigned u = __float_as_uint(f);
    unsigned r = u + 0x7fff + ((u >> 16) & 1);   // round-to-nearest-even
    return (unsigned short)(r >> 16);
}

// ---------------------------------------------------------------------------
// x (fp32) -> xb (bf16), 8 elems/thread
// ---------------------------------------------------------------------------
__global__ __launch_bounds__(256) void conv_x(const float* __restrict__ x,
                                              unsigned short* __restrict__ xb)
{
    int g = blockIdx.x * 256 + threadIdx.x;          // 4,194,304 threads
    const float4* src = (const float4*)x + (size_t)g * 2;
    float4 a = src[0], b = src[1];
    bf16x8 o;
    o[0] = (short)f2bf(a.x); o[1] = (short)f2bf(a.y);
    o[2] = (short)f2bf(a.z); o[3] = (short)f2bf(a.w);
    o[4] = (short)f2bf(b.x); o[5] = (short)f2bf(b.y);
    o[6] = (short)f2bf(b.z); o[7] = (short)f2bf(b.w);
    *(bf16x8*)(xb + (size_t)g * 8) = o;
}

// ---------------------------------------------------------------------------
// Transpose-convert all weights: W[k][n] fp32 -> Wt[n][k] bf16.
// Regions (elems): Wf 65536 (1024x64) | W0 4096 (64x64) | W1 16384 (64x256)
//                | Wmu 65536 (256x256) | Wvar 65536 (256x256)   total 217088
// ---------------------------------------------------------------------------
__global__ __launch_bounds__(256) void prep_weights(
    const float* __restrict__ Wf,  const float* __restrict__ W0,
    const float* __restrict__ W1,  const float* __restrict__ Wmu,
    const float* __restrict__ Wvar,
    unsigned short* __restrict__ Wft, unsigned short* __restrict__ W0t,
    unsigned short* __restrict__ W1t, unsigned short* __restrict__ Wmt,
    unsigned short* __restrict__ Wvt)
{
    int gid = blockIdx.x * 256 + threadIdx.x;
    const float* src; unsigned short* dst; int off, K, N;
    if (gid < 65536)       { src = Wf;  dst = Wft; off = gid;          K = 1024; N = 64;  }
    else if (gid < 69632)  { src = W0;  dst = W0t; off = gid - 65536;  K = 64;   N = 64;  }
    else if (gid < 86016)  { src = W1;  dst = W1t; off = gid - 69632;  K = 64;   N = 256; }
    else if (gid < 151552) { src = Wmu; dst = Wmt; off = gid - 86016;  K = 256;  N = 256; }
    else                   { src = Wvar;dst = Wvt; off = gid - 151552; K = 256;  N = 256; }
    int k = off / N, n = off % N;      // N is power of 2
    dst[(size_t)n * K + k] = f2bf(src[off]);
}

// ---------------------------------------------------------------------------
// Fused MLP: h3 = relu(relu(xb@Wf + bf)@W0 + b0)@W1 + b1)  [64 rows/block]
// h1/h2 live in LDS; only h3 (bf16) goes to HBM.
// All LDS tiles use the 16B-chunk XOR swizzle (chunk j of row r at j^(r&7)).
// ---------------------------------------------------------------------------
__global__ __launch_bounds__(256) void mlp_fused(
    const unsigned short* __restrict__ xb,
    const unsigned short* __restrict__ Wft, const float* __restrict__ b_feat,
    const unsigned short* __restrict__ W0t, const float* __restrict__ b0,
    const unsigned short* __restrict__ W1t, const float* __restrict__ b1,
    unsigned short* __restrict__ h3b)
{
    __shared__ __align__(16) char lds[65536];
    short* Xs  = (short*)lds;            // 8 KB: x slice   [64r x 8 chunks]
    short* Ws  = (short*)(lds + 8192);   // 8 KB: Wf/W0 slice
    short* H1  = (short*)(lds + 16384);  // 8 KB
    short* H2  = (short*)(lds + 24576);  // 8 KB
    short* W1s = (short*)(lds + 32768);  // 32 KB: W1t full [256n x 8 chunks]

    const int t   = threadIdx.x;
    const int w   = t >> 6;
    const int l   = t & 63;
    const int q   = l >> 4;
    const int j16 = l & 15;
    const int rowBase = blockIdx.x * 64;
    const int m = 16 * w + j16;          // block-local row this lane's A-frags use

    // ================= stage 1: h1 = xb @ Wf + bf (K=1024, no relu) ========
    f32x4 acc1[4];
#pragma unroll
    for (int v = 0; v < 4; ++v) acc1[v] = (f32x4){0.f, 0.f, 0.f, 0.f};

    for (int ks = 0; ks < 16; ++ks) {
        __syncthreads();
#pragma unroll
        for (int i = 0; i < 2; ++i) {
            int p  = i * 256 + t;
            int r  = p >> 3;
            int js = p & 7;
            int j  = js ^ (r & 7);
            // x slice
            const unsigned short* gx = xb + (size_t)(rowBase + r) * IN_D + ks * 64 + j * 8;
            void* dx = (char*)Xs + (size_t)(i * 256 + w * 64) * 16;
            __builtin_amdgcn_global_load_lds(
                (const __attribute__((address_space(1))) void*)gx,
                (__attribute__((address_space(3))) void*)dx, 16, 0, 0);
            // Wf slice: Wft[n][1024], n=r
            const unsigned short* gw = Wft + (size_t)r * IN_D + ks * 64 + j * 8;
            void* dw = (char*)Ws + (size_t)(i * 256 + w * 64) * 16;
            __builtin_amdgcn_global_load_lds(
                (const __attribute__((address_space(1))) void*)gw,
                (__attribute__((address_space(3))) void*)dw, 16, 0, 0);
        }
        __syncthreads();
#pragma unroll
        for (int kk = 0; kk < 2; ++kk) {
            int jw = kk * 4 + q;
            bf16x8 af = *(const bf16x8*)((char*)Xs + (size_t)(m * 8 + (jw ^ (m & 7))) * 16);
#pragma unroll
            for (int v = 0; v < 4; ++v) {
                int n = 16 * v + j16;
                bf16x8 bf = *(const bf16x8*)((char*)Ws + (size_t)(n * 8 + (jw ^ (n & 7))) * 16);
                acc1[v] = __builtin_amdgcn_mfma_f32_16x16x32_bf16(af, bf, acc1[v], 0, 0, 0);
            }
        }
    }
    // epilogue 1 -> H1 (bf16, A-frag/swizzled row-major)
#pragma unroll
    for (int v = 0; v < 4; ++v) {
        int c = 16 * v + j16;
        float bb = b_feat[c];
#pragma unroll
        for (int rg = 0; rg < 4; ++rg) {
            int r = 16 * w + q * 4 + rg;
            float h = acc1[v][rg] + bb;
            *(short*)((char*)H1 + (size_t)(r * 8 + ((c >> 3) ^ (r & 7))) * 16 + (c & 7) * 2)
                = (short)f2bf(h);
        }
    }

    // ================= stage 2: h2 = relu(h1 @ W0 + b0) (K=64) =============
    __syncthreads();   // H1 visible; Ws free
#pragma unroll
    for (int i = 0; i < 2; ++i) {
        int p  = i * 256 + t;
        int n  = p >> 3;
        int js = p & 7;
        int j  = js ^ (n & 7);
        const unsigned short* gw = W0t + (size_t)n * 64 + j * 8;
        void* dw = (char*)Ws + (size_t)(i * 256 + w * 64) * 16;
        __builtin_amdgcn_global_load_lds(
            (const __attribute__((address_space(1))) void*)gw,
            (__attribute__((address_space(3))) void*)dw, 16, 0, 0);
    }
    __syncthreads();
    f32x4 acc2[4];
#pragma unroll
    for (int v = 0; v < 4; ++v) acc2[v] = (f32x4){0.f, 0.f, 0.f, 0.f};
#pragma unroll
    for (int kk = 0; kk < 2; ++kk) {
        int jw = kk * 4 + q;
        bf16x8 af = *(const bf16x8*)((char*)H1 + (size_t)(m * 8 + (jw ^ (m & 7))) * 16);
#pragma unroll
        for (int v = 0; v < 4; ++v) {
            int n = 16 * v + j16;
            bf16x8 bf = *(const bf16x8*)((char*)Ws + (size_t)(n * 8 + (jw ^ (n & 7))) * 16);
            acc2[v] = __builtin_amdgcn_mfma_f32_16x16x32_bf16(af, bf, acc2[v], 0, 0, 0);
        }
    }
#pragma unroll
    for (int v = 0; v < 4; ++v) {
        int c = 16 * v + j16;
        float bb = b0[c];
#pragma unroll
        for (int rg = 0; rg < 4; ++rg) {
            int r = 16 * w + q * 4 + rg;
            float h = fmaxf(acc2[v][rg] + bb, 0.f);
            *(short*)((char*)H2 + (size_t)(r * 8 + ((c >> 3) ^ (r & 7))) * 16 + (c & 7) * 2)
                = (short)f2bf(h);
        }
    }

    // ================= stage 3: h3 = relu(h2 @ W1 + b1) (K=64, N=256) ======
    __syncthreads();
#pragma unroll
    for (int i = 0; i < 8; ++i) {
        int p  = i * 256 + t;
        int n  = p >> 3;
        int js = p & 7;
        int j  = js ^ (n & 7);
        const unsigned short* gw = W1t + (size_t)n * 64 + j * 8;
        void* dw = (char*)W1s + (size_t)(i * 256 + w * 64) * 16;
        __builtin_amdgcn_global_load_lds(
            (const __attribute__((address_space(1))) void*)gw,
            (__attribute__((address_space(3))) void*)dw, 16, 0, 0);
    }
    __syncthreads();
    f32x4 acc3[16];
#pragma unroll
    for (int v = 0; v < 16; ++v) acc3[v] = (f32x4){0.f, 0.f, 0.f, 0.f};
#pragma unroll
    for (int kk = 0; kk < 2; ++kk) {
        int jw = kk * 4 + q;
        bf16x8 af = *(const bf16x8*)((char*)H2 + (size_t)(m * 8 + (jw ^ (m & 7))) * 16);
#pragma unroll
        for (int v = 0; v < 16; ++v) {
            int n = 16 * v + j16;
            bf16x8 bf = *(const bf16x8*)((char*)W1s + (size_t)(n * 8 + (jw ^ (n & 7))) * 16);
            acc3[v] = __builtin_amdgcn_mfma_f32_16x16x32_bf16(af, bf, acc3[v], 0, 0, 0);
        }
    }
#pragma unroll
    for (int v = 0; v < 16; ++v) {
        int c = 16 * v + j16;
        float bb = b1[c];
#pragma unroll
        for (int rg = 0; rg < 4; ++rg) {
            int row = rowBase + 16 * w + q * 4 + rg;
            float h = fmaxf(acc3[v][rg] + bb, 0.f);
            h3b[(size_t)row * COMM + c] = f2bf(h);
        }
    }
}

// ---------------------------------------------------------------------------
// Head: [mu|lv] = h3b @ [Wmu|Wvar] + bias; sample = mu + eps*exp(0.5*lv);
// KL partials. 64 rows/block, paired 64-col chunks.
// ---------------------------------------------------------------------------
__global__ __launch_bounds__(256) void head_mfma(
    const unsigned short* __restrict__ h3b,
    const unsigned short* __restrict__ Wmt, const float* __restrict__ bmu,
    const unsigned short* __restrict__ Wvt, const float* __restrict__ bvar,
    const float* __restrict__ eps,
    float* __restrict__ sample,
    unsigned short* __restrict__ sampleb,
    float* __restrict__ klpart)
{
    __shared__ __align__(16) char lds[49152];
    short* H3 = (short*)lds;             // 32 KB: [64r x 32 chunks], swizzled
    short* Wm = (short*)(lds + 32768);   // 8 KB
    short* Wv = (short*)(lds + 40960);   // 8 KB

    const int t   = threadIdx.x;
    const int w   = t >> 6;
    const int l   = t & 63;
    const int q   = l >> 4;
    const int j16 = l & 15;
    const int rowBase = blockIdx.x * 64;
    const int m = 16 * w + j16;

    // stage H3 (2048 chunks, 8/thread); 32-chunk-row swizzle
#pragma unroll
    for (int i = 0; i < 8; ++i) {
        int p  = i * 256 + t;
        int r  = p >> 5;
        int js = p & 31;
        int j  = (js & 24) | ((js & 7) ^ (r & 7));
        const unsigned short* g = h3b + (size_t)(rowBase + r) * COMM + j * 8;
        void* d = (char*)H3 + (size_t)(i * 256 + w * 64) * 16;
        __builtin_amdgcn_global_load_lds(
            (const __attribute__((address_space(1))) void*)g,
            (__attribute__((address_space(3))) void*)d, 16, 0, 0);
    }

    float kl = 0.f;
    for (int c = 0; c < 4; ++c) {         // 64-col chunk of mu & lv
        f32x4 am[4], av[4];
#pragma unroll
        for (int v = 0; v < 4; ++v) {
            am[v] = (f32x4){0.f, 0.f, 0.f, 0.f};
            av[v] = (f32x4){0.f, 0.f, 0.f, 0.f};
        }
        for (int ks = 0; ks < 4; ++ks) {  // K slices of 64
            __syncthreads();
#pragma unroll
            for (int i = 0; i < 2; ++i) {
                int p  = i * 256 + t;
                int n  = p >> 3;          // local col 0..63
                int js = p & 7;
                int j  = js ^ (n & 7);
                const unsigned short* gm =
                    Wmt + (size_t)(c * 64 + n) * COMM + ks * 64 + j * 8;
                const unsigned short* gv =
                    Wvt + (size_t)(c * 64 + n) * COMM + ks * 64 + j * 8;
                void* dm = (char*)Wm + (size_t)(i * 256 + w * 64) * 16;
                void* dv = (char*)Wv + (size_t)(i * 256 + w * 64) * 16;
                __builtin_amdgcn_global_load_lds(
                    (const __attribute__((address_space(1))) void*)gm,
                    (__attribute__((address_space(3))) void*)dm, 16, 0, 0);
                __builtin_amdgcn_global_load_lds(
                    (const __attribute__((address_space(1))) void*)gv,
                    (__attribute__((address_space(3))) void*)dv, 16, 0, 0);
            }
            __syncthreads();
#pragma unroll
            for (int kk = 0; kk < 2; ++kk) {
                int jwg = ks * 8 + kk * 4 + q;   // global k-chunk 0..31
                bf16x8 af = *(const bf16x8*)((char*)H3 +
                    (size_t)(m * 32 + ((jwg & 24) | ((jwg & 7) ^ (m & 7)))) * 16);
                int jw = kk * 4 + q;
#pragma unroll
                for (int v = 0; v < 4; ++v) {
                    int n = 16 * v + j16;
                    size_t pos = (size_t)(n * 8 + (jw ^ (n & 7))) * 16;
                    bf16x8 bm = *(const bf16x8*)((char*)Wm + pos);
                    bf16x8 bv = *(const bf16x8*)((char*)Wv + pos);
                    am[v] = __builtin_amdgcn_mfma_f32_16x16x32_bf16(af, bm, am[v], 0, 0, 0);
                    av[v] = __builtin_amdgcn_mfma_f32_16x16x32_bf16(af, bv, av[v], 0, 0, 0);
                }
            }
        }
        // epilogue for this 64-col chunk
#pragma unroll
        for (int v = 0; v < 4; ++v) {
            int col = c * 64 + 16 * v + j16;
            float bm_ = bmu[col];
            float bv_ = bvar[col];
#pragma unroll
            for (int rg = 0; rg < 4; ++rg) {
                int row = rowBase + 16 * w + q * 4 + rg;
                float mu = am[v][rg] + bm_;
                float lv = av[v][rg] + bv_;
                float e  = expf(0.5f * lv);
                float s  = mu + eps[(size_t)row * COMM + col] * e;
                sample [(size_t)row * COMM + col] = s;
                sampleb[(size_t)row * COMM + col] = f2bf(s);
                kl += 1.f + lv - mu * mu - e * e;
            }
        }
    }
#pragma unroll
    for (int off = 32; off; off >>= 1) kl += __shfl_down(kl, off);
    __shared__ float wsum[4];
    if (l == 0) wsum[w] = kl;
    __syncthreads();
    if (t == 0)
        klpart[blockIdx.x] = wsum[0] + wsum[1] + wsum[2] + wsum[3];
}

// ---------------------------------------------------------------------------
// pnorm[k] = ||protos[k]||^2 (fp32) and bf16 conversion of protos.
// ---------------------------------------------------------------------------
__global__ __launch_bounds__(256) void pnorm_conv_kernel(const float* __restrict__ protos,
                                                         float* __restrict__ pnorm,
                                                         unsigned short* __restrict__ protosb)
{
    int g    = blockIdx.x * 256 + threadIdx.x;
    int wave = g >> 6;
    int lane = g & 63;
    float4 v = *(const float4*)&protos[(size_t)wave * COMM + lane * 4];
    ushort4 b;
    b.x = f2bf(v.x); b.y = f2bf(v.y); b.z = f2bf(v.z); b.w = f2bf(v.w);
    *(ushort4*)&protosb[(size_t)wave * COMM + lane * 4] = b;
    float s = v.x * v.x + v.y * v.y + v.z * v.z + v.w * v.w;
#pragma unroll
    for (int off = 32; off; off >>= 1) s += __shfl_down(s, off);
    if (lane == 0) pnorm[wave] = s;
}

// ---------------------------------------------------------------------------
// MFMA distance + argmin (unchanged from round 2).
// ---------------------------------------------------------------------------
#define SPLITS 4
#define SPAN   (NPROTO / SPLITS)   // 2048
#define NT     (SPAN / 128)        // 16 proto tiles per block

__global__ __launch_bounds__(256) void vq_argmin_mfma(
    const unsigned short* __restrict__ sampleb,
    const unsigned short* __restrict__ protosb,
    const float* __restrict__ pnorm,
    float* __restrict__ minval,
    int* __restrict__ minidx)
{
    __shared__ __align__(16) short As[128 * 256];  // 64 KB
    __shared__ __align__(16) short Bs[128 * 64];   // 16 KB

    const int t   = threadIdx.x;
    const int w   = t >> 6;
    const int l   = t & 63;
    const int q   = l >> 4;
    const int j16 = l & 15;
    const int wrow = (w >> 1) * 64;
    const int wcol = (w & 1) * 64;
    const int rowBase = blockIdx.x * 128;
    const int pBase   = blockIdx.y * SPAN;

#pragma unroll
    for (int i = 0; i < 16; ++i) {
        int p  = i * 256 + t;
        int r  = p >> 5;
        int js = p & 31;
        int j  = (js & 24) | ((js & 7) ^ (r & 7));
        const unsigned short* g = sampleb + (size_t)(rowBase + r) * COMM + j * 8;
        void* lds = (char*)As + (size_t)(i * 256 + w * 64) * 16;
        __builtin_amdgcn_global_load_lds(
            (const __attribute__((address_space(1))) void*)g,
            (__attribute__((address_space(3))) void*)lds, 16, 0, 0);
    }

    float bestv[16];
    int   besti[16];
#pragma unroll
    for (int s = 0; s < 16; ++s) { bestv[s] = FLT_MAX; besti[s] = 0; }

    for (int pt = 0; pt < NT; ++pt) {
        const int pTile = pBase + pt * 128;
        f32x4 acc[4][4];
#pragma unroll
        for (int u = 0; u < 4; ++u)
#pragma unroll
            for (int v = 0; v < 4; ++v) acc[u][v] = (f32x4){0.f, 0.f, 0.f, 0.f};

        for (int ks = 0; ks < 4; ++ks) {
            __syncthreads();
#pragma unroll
            for (int i = 0; i < 4; ++i) {
                int p  = i * 256 + t;
                int r  = p >> 3;
                int js = p & 7;
                int j  = js ^ (r & 7);
                const unsigned short* g =
                    protosb + (size_t)(pTile + r) * COMM + ks * 64 + j * 8;
                void* lds = (char*)Bs + (size_t)(i * 256 + w * 64) * 16;
                __builtin_amdgcn_global_load_lds(
                    (const __attribute__((address_space(1))) void*)g,
                    (__attribute__((address_space(3))) void*)lds, 16, 0, 0);
            }
            __syncthreads();
#pragma unroll
            for (int s = 0; s < 2; ++s) {
                const int kk = ks * 2 + s;
                bf16x8 af[4], bfv[4];
#pragma unroll
                for (int u = 0; u < 4; ++u) {
                    int mm  = wrow + 16 * u + j16;
                    int jw  = kk * 4 + q;
                    int pos = mm * 32 + ((jw & 24) | ((jw & 7) ^ (mm & 7)));
                    af[u] = *(const bf16x8*)((const char*)As + (size_t)pos * 16);
                }
#pragma unroll
                for (int v = 0; v < 4; ++v) {
                    int n   = wcol + 16 * v + j16;
                    int jw  = s * 4 + q;
                    int pos = n * 8 + (jw ^ (n & 7));
                    bfv[v] = *(const bf16x8*)((const char*)Bs + (size_t)pos * 16);
                }
#pragma unroll
                for (int u = 0; u < 4; ++u)
#pragma unroll
                    for (int v = 0; v < 4; ++v)
                        acc[u][v] = __builtin_amdgcn_mfma_f32_16x16x32_bf16(
                            af[u], bfv[v], acc[u][v], 0, 0, 0);
            }
        }
#pragma unroll
        for (int v = 0; v < 4; ++v) {
            int col  = pTile + wcol + 16 * v + j16;
            float pn = pnorm[col];
#pragma unroll
            for (int u = 0; u < 4; ++u)
#pragma unroll
                for (int rg = 0; rg < 4; ++rg) {
                    float sc   = pn - 2.f * acc[u][v][rg];
                    int   slot = u * 4 + rg;
                    if (sc < bestv[slot]) { bestv[slot] = sc; besti[slot] = col; }
                }
        }
    }
#pragma unroll
    for (int off = 1; off < 16; off <<= 1) {
#pragma unroll
        for (int s = 0; s < 16; ++s) {
            float ov = __shfl_xor(bestv[s], off);
            int   oi = __shfl_xor(besti[s], off);
            if (ov < bestv[s] || (ov == bestv[s] && oi < besti[s])) {
                bestv[s] = ov; besti[s] = oi;
            }
        }
    }
    __syncthreads();
    float* cv = (float*)Bs;
    int*   ci = ((int*)Bs) + 256;
    if (j16 == 0) {
#pragma unroll
        for (int u = 0; u < 4; ++u)
#pragma unroll
            for (int rg = 0; rg < 4; ++rg) {
                int row = wrow + 16 * u + 4 * q + rg;
                cv[(w & 1) * 128 + row] = bestv[u * 4 + rg];
                ci[(w & 1) * 128 + row] = besti[u * 4 + rg];
            }
    }
    __syncthreads();
    if (t < 128) {
        float v0 = cv[t];       int i0 = ci[t];
        float v1 = cv[128 + t]; int i1 = ci[128 + t];
        if (v1 < v0 || (v1 == v0 && i1 < i0)) { v0 = v1; i0 = i1; }
        minval[(size_t)blockIdx.y * B_SZ + rowBase + t] = v0;
        minidx[(size_t)blockIdx.y * B_SZ + rowBase + t] = i0;
    }
}

// ---------------------------------------------------------------------------
__global__ __launch_bounds__(256) void combine_kernel(const float* __restrict__ minval,
                                                      const int* __restrict__ minidx,
                                                      int* __restrict__ idx)
{
    int i = blockIdx.x * 256 + threadIdx.x;
    float bv = minval[i];
    int   bi = minidx[i];
#pragma unroll
    for (int s = 1; s < SPLITS; ++s) {
        float v = minval[(size_t)s * B_SZ + i];
        int   j = minidx[(size_t)s * B_SZ + i];
        if (v < bv || (v == bv && j < bi)) { bv = v; bi = j; }
    }
    idx[i] = bi;
}

// ---------------------------------------------------------------------------
__global__ __launch_bounds__(256) void gather_kernel(const float* __restrict__ sample,
                                                     const float* __restrict__ protos,
                                                     const int* __restrict__ idx,
                                                     float* __restrict__ out,
                                                     float* __restrict__ msepart)
{
    int t  = threadIdx.x;
    int rb = blockIdx.x * 8;
    float part = 0.f;
#pragma unroll
    for (int u = 0; u < 8; ++u) {
        int i  = rb + u;
        int id = idx[i];
        float qv = protos[(size_t)id * COMM + t];
        float s  = sample[(size_t)i * COMM + t];
        float d  = qv - s;
        out[(size_t)i * COMM + t] = s + d;
        part += d * d;
    }
#pragma unroll
    for (int off = 32; off; off >>= 1) part += __shfl_down(part, off);
    __shared__ float wsum[4];
    if ((t & 63) == 0) wsum[t >> 6] = part;
    __syncthreads();
    if (t == 0) msepart[blockIdx.x] = wsum[0] + wsum[1] + wsum[2] + wsum[3];
}

// ---------------------------------------------------------------------------
__global__ __launch_bounds__(256) void finalize_kernel(const float* __restrict__ klpart, int nkl,
                                                       const float* __restrict__ msepart, int nmse,
                                                       float* __restrict__ out)
{
    int t = threadIdx.x;
    double kl = 0.0, mse = 0.0;
    for (int i = t; i < nkl;  i += 256) kl  += (double)klpart[i];
    for (int i = t; i < nmse; i += 256) mse += (double)msepart[i];
#pragma unroll
    for (int off = 32; off; off >>= 1) {
        kl  += __shfl_down(kl, off);
        mse += __shfl_down(mse, off);
    }
    __shared__ double skl[4], smse[4];
    if ((t & 63) == 0) { skl[t >> 6] = kl; smse[t >> 6] = mse; }
    __syncthreads();
    if (t == 0) {
        double K  = skl[0] + skl[1] + skl[2] + skl[3];
        double M  = smse[0] + smse[1] + smse[2] + smse[3];
        double kld = -0.5 * K / (double)B_SZ;
        double vq  = 1.25 * M / ((double)B_SZ * (double)COMM);
        out[(size_t)B_SZ * COMM]     = (float)(kld + vq);
        out[(size_t)B_SZ * COMM + 1] = (float)kld;
    }
}

// ---------------------------------------------------------------------------
extern "C" void kernel_launch(void* const* d_in, const int* in_sizes, int n_in,
                              void* d_out, int out_size, void* d_ws, size_t ws_size,
                              hipStream_t stream)
{
    const float* x      = (const float*)d_in[0];
    const float* eps    = (const float*)d_in[1];
    const float* W_feat = (const float*)d_in[2];
    const float* b_feat = (const float*)d_in[3];
    const float* W0     = (const float*)d_in[4];
    const float* b0     = (const float*)d_in[5];
    const float* W1     = (const float*)d_in[6];
    const float* b1     = (const float*)d_in[7];
    const float* W_mu   = (const float*)d_in[8];
    const float* b_mu   = (const float*)d_in[9];
    const float* W_var  = (const float*)d_in[10];
    const float* b_var  = (const float*)d_in[11];
    const float* protos = (const float*)d_in[12];
    float* out = (float*)d_out;

    char* wsb = (char*)d_ws;
    size_t off = 0;
    auto alloc = [&](size_t bytes) -> void* {
        void* p = wsb + off;
        off = (off + bytes + 255) & ~(size_t)255;
        return p;
    };
    unsigned short* xb      = (unsigned short*)alloc((size_t)B_SZ * IN_D * 2);
    unsigned short* Wft     = (unsigned short*)alloc((size_t)IN_D * HID * 2);
    unsigned short* W0t     = (unsigned short*)alloc((size_t)HID * HID * 2);
    unsigned short* W1t     = (unsigned short*)alloc((size_t)HID * COMM * 2);
    unsigned short* Wmt     = (unsigned short*)alloc((size_t)COMM * COMM * 2);
    unsigned short* Wvt     = (unsigned short*)alloc((size_t)COMM * COMM * 2);
    unsigned short* h3b     = (unsigned short*)alloc((size_t)B_SZ * COMM * 2);
    float*          sample  = (float*)alloc((size_t)B_SZ * COMM * 4);
    unsigned short* sampleb = (unsigned short*)alloc((size_t)B_SZ * COMM * 2);
    unsigned short* protosb = (unsigned short*)alloc((size_t)NPROTO * COMM * 2);
    float*          pnorm   = (float*)alloc((size_t)NPROTO * 4);
    float*          minval  = (float*)alloc((size_t)SPLITS * B_SZ * 4);
    int*            minidx  = (int*)  alloc((size_t)SPLITS * B_SZ * 4);
    int*            idx     = (int*)  alloc((size_t)B_SZ * 4);
    float*          klpart  = (float*)alloc(512 * 4);
    float*          msepart = (float*)alloc(4096 * 4);

    conv_x<<<16384, 256, 0, stream>>>(x, xb);
    prep_weights<<<848, 256, 0, stream>>>(W_feat, W0, W1, W_mu, W_var,
                                          Wft, W0t, W1t, Wmt, Wvt);
    pnorm_conv_kernel<<<NPROTO / 4, 256, 0, stream>>>(protos, pnorm, protosb);
    mlp_fused<<<B_SZ / 64, 256, 0, stream>>>(xb, Wft, b_feat, W0t, b0, W1t, b1, h3b);
    head_mfma<<<B_SZ / 64, 256, 0, stream>>>(h3b, Wmt, b_mu, Wvt, b_var, eps,
                                             sample, sampleb, klpart);
    vq_argmin_mfma<<<dim3(B_SZ / 128, SPLITS), 256, 0, stream>>>(sampleb, protosb, pnorm,
                                                                 minval, minidx);
    combine_kernel<<<B_SZ / 256, 256, 0, stream>>>(minval, minidx, idx);
    gather_kernel<<<B_SZ / 8, 256, 0, stream>>>(sample, protos, idx, out, msepart);
    finalize_kernel<<<1, 256, 0, stream>>>(klpart, 512, msepart, 4096, out);
}

// Round 4
// 428.553 us; speedup vs baseline: 31.0972x; 1.0955x over previous
//
#include <hip/hip_runtime.h>
#include <cfloat>

#define B_SZ   32768
#define IN_D   1024
#define HID    64
#define COMM   256
#define NPROTO 8192

#define SSCALE 12.0f
#define PSCALE 1.0e6f

typedef __attribute__((ext_vector_type(8))) short bf16x8;
typedef __attribute__((ext_vector_type(4))) float f32x4;
typedef __attribute__((ext_vector_type(4))) int   i32x4;

#define AS1 __attribute__((address_space(1)))
#define AS3 __attribute__((address_space(3)))

__device__ __forceinline__ unsigned short f2bf(float f) {
    unsigned u = __float_as_uint(f);
    unsigned r = u + 0x7fff + ((u >> 16) & 1);   // round-to-nearest-even
    return (unsigned short)(r >> 16);
}

__device__ __forceinline__ int f2i8(float f, float scale) {
    float v = fminf(fmaxf(f * scale, -127.f), 127.f);
    return __float2int_rn(v);
}

// ---------------------------------------------------------------------------
// Transpose-convert all weights: W[k][n] fp32 -> Wt[n][k] bf16.
// ---------------------------------------------------------------------------
__global__ __launch_bounds__(256) void prep_weights(
    const float* __restrict__ Wf,  const float* __restrict__ W0,
    const float* __restrict__ W1,  const float* __restrict__ Wmu,
    const float* __restrict__ Wvar,
    unsigned short* __restrict__ Wft, unsigned short* __restrict__ W0t,
    unsigned short* __restrict__ W1t, unsigned short* __restrict__ Wmt,
    unsigned short* __restrict__ Wvt)
{
    int gid = blockIdx.x * 256 + threadIdx.x;
    const float* src; unsigned short* dst; int off, K, N;
    if (gid < 65536)       { src = Wf;  dst = Wft; off = gid;          K = 1024; N = 64;  }
    else if (gid < 69632)  { src = W0;  dst = W0t; off = gid - 65536;  K = 64;   N = 64;  }
    else if (gid < 86016)  { src = W1;  dst = W1t; off = gid - 69632;  K = 64;   N = 256; }
    else if (gid < 151552) { src = Wmu; dst = Wmt; off = gid - 86016;  K = 256;  N = 256; }
    else                   { src = Wvar;dst = Wvt; off = gid - 151552; K = 256;  N = 256; }
    int k = off / N, n = off % N;
    dst[(size_t)n * K + k] = f2bf(src[off]);
}

// ---------------------------------------------------------------------------
// pnormS[k] = ||protos[k]||^2 * SSCALE*PSCALE; protoq = int8(protos*PSCALE)
// in tiled layout: [tile=p>>7][chunk jc=k>>4][p&127][16 bytes].
// ---------------------------------------------------------------------------
__global__ __launch_bounds__(256) void pnorm_conv_kernel(const float* __restrict__ protos,
                                                         float* __restrict__ pnormS,
                                                         char* __restrict__ protoq)
{
    int g    = blockIdx.x * 256 + threadIdx.x;
    int p    = g >> 6;
    int lane = g & 63;
    float4 v = *(const float4*)&protos[(size_t)p * COMM + lane * 4];
    int b0 = f2i8(v.x, PSCALE) & 0xff;
    int b1 = f2i8(v.y, PSCALE) & 0xff;
    int b2 = f2i8(v.z, PSCALE) & 0xff;
    int b3 = f2i8(v.w, PSCALE) & 0xff;
    int pk = b0 | (b1 << 8) | (b2 << 16) | (b3 << 24);
    int T = p >> 7, jc = lane >> 2;
    *(int*)(protoq + ((size_t)(T * 16 + jc) * 128 + (p & 127)) * 16 + (lane & 3) * 4) = pk;
    float s = v.x * v.x + v.y * v.y + v.z * v.z + v.w * v.w;
#pragma unroll
    for (int off = 32; off; off >>= 1) s += __shfl_down(s, off);
    if (lane == 0) pnormS[p] = s * (SSCALE * PSCALE);
}

// ---------------------------------------------------------------------------
// Fused MLP with inline x conversion: h3 = relu(relu((x@Wf+bf)@W0+b0)@W1+b1)
// 64 rows/block; h1/h2 in LDS; 16B-chunk XOR swizzle throughout.
// ---------------------------------------------------------------------------
__global__ __launch_bounds__(256) void mlp_fused(
    const float* __restrict__ x,
    const unsigned short* __restrict__ Wft, const float* __restrict__ b_feat,
    const unsigned short* __restrict__ W0t, const float* __restrict__ b0,
    const unsigned short* __restrict__ W1t, const float* __restrict__ b1,
    unsigned short* __restrict__ h3b)
{
    __shared__ __align__(16) char lds[65536];
    short* Xs  = (short*)lds;            // 8 KB
    short* Ws  = (short*)(lds + 8192);   // 8 KB
    short* H1  = (short*)(lds + 16384);  // 8 KB
    short* H2  = (short*)(lds + 24576);  // 8 KB
    short* W1s = (short*)(lds + 32768);  // 32 KB

    const int t   = threadIdx.x;
    const int w   = t >> 6;
    const int l   = t & 63;
    const int q   = l >> 4;
    const int j16 = l & 15;
    const int rowBase = blockIdx.x * 64;
    const int m = 16 * w + j16;

    // x prefetch registers (slice = 64 rows x 64 k fp32)
    float4 xr[2][2];
    int   xp[2];
    auto loadX = [&](int ks) {
#pragma unroll
        for (int i = 0; i < 2; ++i) {
            int p  = i * 256 + t;
            int r  = p >> 3;
            int js = p & 7;
            int j  = js ^ (r & 7);
            const float4* g = (const float4*)(x + (size_t)(rowBase + r) * IN_D + ks * 64 + j * 8);
            xr[i][0] = g[0];
            xr[i][1] = g[1];
            xp[i] = p;
        }
    };

    // ================= stage 1: h1 = x @ Wf + bf (K=1024) ==================
    f32x4 acc1[4];
#pragma unroll
    for (int v = 0; v < 4; ++v) acc1[v] = (f32x4){0.f, 0.f, 0.f, 0.f};

    loadX(0);
    for (int ks = 0; ks < 16; ++ks) {
        __syncthreads();
        // write converted x slice into Xs
#pragma unroll
        for (int i = 0; i < 2; ++i) {
            bf16x8 o;
            o[0] = (short)f2bf(xr[i][0].x); o[1] = (short)f2bf(xr[i][0].y);
            o[2] = (short)f2bf(xr[i][0].z); o[3] = (short)f2bf(xr[i][0].w);
            o[4] = (short)f2bf(xr[i][1].x); o[5] = (short)f2bf(xr[i][1].y);
            o[6] = (short)f2bf(xr[i][1].z); o[7] = (short)f2bf(xr[i][1].w);
            *(bf16x8*)((char*)Xs + (size_t)xp[i] * 16) = o;
        }
        // stage Wf slice
#pragma unroll
        for (int i = 0; i < 2; ++i) {
            int p  = i * 256 + t;
            int r  = p >> 3;
            int js = p & 7;
            int j  = js ^ (r & 7);
            const unsigned short* gw = Wft + (size_t)r * IN_D + ks * 64 + j * 8;
            void* dw = (char*)Ws + (size_t)(i * 256 + w * 64) * 16;
            __builtin_amdgcn_global_load_lds(
                (const AS1 void*)gw, (AS3 void*)dw, 16, 0, 0);
        }
        if (ks < 15) loadX(ks + 1);
        __syncthreads();
#pragma unroll
        for (int kk = 0; kk < 2; ++kk) {
            int jw = kk * 4 + q;
            bf16x8 af = *(const bf16x8*)((char*)Xs + (size_t)(m * 8 + (jw ^ (m & 7))) * 16);
#pragma unroll
            for (int v = 0; v < 4; ++v) {
                int n = 16 * v + j16;
                bf16x8 bf = *(const bf16x8*)((char*)Ws + (size_t)(n * 8 + (jw ^ (n & 7))) * 16);
                acc1[v] = __builtin_amdgcn_mfma_f32_16x16x32_bf16(af, bf, acc1[v], 0, 0, 0);
            }
        }
    }
#pragma unroll
    for (int v = 0; v < 4; ++v) {
        int c = 16 * v + j16;
        float bb = b_feat[c];
#pragma unroll
        for (int rg = 0; rg < 4; ++rg) {
            int r = 16 * w + q * 4 + rg;
            float h = acc1[v][rg] + bb;
            *(short*)((char*)H1 + (size_t)(r * 8 + ((c >> 3) ^ (r & 7))) * 16 + (c & 7) * 2)
                = (short)f2bf(h);
        }
    }

    // ================= stage 2: h2 = relu(h1 @ W0 + b0) ====================
    __syncthreads();
#pragma unroll
    for (int i = 0; i < 2; ++i) {
        int p  = i * 256 + t;
        int n  = p >> 3;
        int js = p & 7;
        int j  = js ^ (n & 7);
        const unsigned short* gw = W0t + (size_t)n * 64 + j * 8;
        void* dw = (char*)Ws + (size_t)(i * 256 + w * 64) * 16;
        __builtin_amdgcn_global_load_lds(
            (const AS1 void*)gw, (AS3 void*)dw, 16, 0, 0);
    }
    __syncthreads();
    f32x4 acc2[4];
#pragma unroll
    for (int v = 0; v < 4; ++v) acc2[v] = (f32x4){0.f, 0.f, 0.f, 0.f};
#pragma unroll
    for (int kk = 0; kk < 2; ++kk) {
        int jw = kk * 4 + q;
        bf16x8 af = *(const bf16x8*)((char*)H1 + (size_t)(m * 8 + (jw ^ (m & 7))) * 16);
#pragma unroll
        for (int v = 0; v < 4; ++v) {
            int n = 16 * v + j16;
            bf16x8 bf = *(const bf16x8*)((char*)Ws + (size_t)(n * 8 + (jw ^ (n & 7))) * 16);
            acc2[v] = __builtin_amdgcn_mfma_f32_16x16x32_bf16(af, bf, acc2[v], 0, 0, 0);
        }
    }
#pragma unroll
    for (int v = 0; v < 4; ++v) {
        int c = 16 * v + j16;
        float bb = b0[c];
#pragma unroll
        for (int rg = 0; rg < 4; ++rg) {
            int r = 16 * w + q * 4 + rg;
            float h = fmaxf(acc2[v][rg] + bb, 0.f);
            *(short*)((char*)H2 + (size_t)(r * 8 + ((c >> 3) ^ (r & 7))) * 16 + (c & 7) * 2)
                = (short)f2bf(h);
        }
    }

    // ================= stage 3: h3 = relu(h2 @ W1 + b1) (N=256) ============
    __syncthreads();
#pragma unroll
    for (int i = 0; i < 8; ++i) {
        int p  = i * 256 + t;
        int n  = p >> 3;
        int js = p & 7;
        int j  = js ^ (n & 7);
        const unsigned short* gw = W1t + (size_t)n * 64 + j * 8;
        void* dw = (char*)W1s + (size_t)(i * 256 + w * 64) * 16;
        __builtin_amdgcn_global_load_lds(
            (const AS1 void*)gw, (AS3 void*)dw, 16, 0, 0);
    }
    __syncthreads();
    f32x4 acc3[16];
#pragma unroll
    for (int v = 0; v < 16; ++v) acc3[v] = (f32x4){0.f, 0.f, 0.f, 0.f};
#pragma unroll
    for (int kk = 0; kk < 2; ++kk) {
        int jw = kk * 4 + q;
        bf16x8 af = *(const bf16x8*)((char*)H2 + (size_t)(m * 8 + (jw ^ (m & 7))) * 16);
#pragma unroll
        for (int v = 0; v < 16; ++v) {
            int n = 16 * v + j16;
            bf16x8 bf = *(const bf16x8*)((char*)W1s + (size_t)(n * 8 + (jw ^ (n & 7))) * 16);
            acc3[v] = __builtin_amdgcn_mfma_f32_16x16x32_bf16(af, bf, acc3[v], 0, 0, 0);
        }
    }
#pragma unroll
    for (int v = 0; v < 16; ++v) {
        int c = 16 * v + j16;
        float bb = b1[c];
#pragma unroll
        for (int rg = 0; rg < 4; ++rg) {
            int row = rowBase + 16 * w + q * 4 + rg;
            float h = fmaxf(acc3[v][rg] + bb, 0.f);
            h3b[(size_t)row * COMM + c] = f2bf(h);
        }
    }
}

// ---------------------------------------------------------------------------
// Head: mu/lv GEMMs + reparameterize + KL partials; emits fp32 sample and
// int8 sampleq (row-major) for the i8 scoring kernel.
// ---------------------------------------------------------------------------
__global__ __launch_bounds__(256) void head_mfma(
    const unsigned short* __restrict__ h3b,
    const unsigned short* __restrict__ Wmt, const float* __restrict__ bmu,
    const unsigned short* __restrict__ Wvt, const float* __restrict__ bvar,
    const float* __restrict__ eps,
    float* __restrict__ sample,
    char* __restrict__ sampleq,
    float* __restrict__ klpart)
{
    __shared__ __align__(16) char lds[49152];
    short* H3 = (short*)lds;
    short* Wm = (short*)(lds + 32768);
    short* Wv = (short*)(lds + 40960);

    const int t   = threadIdx.x;
    const int w   = t >> 6;
    const int l   = t & 63;
    const int q   = l >> 4;
    const int j16 = l & 15;
    const int rowBase = blockIdx.x * 64;
    const int m = 16 * w + j16;

#pragma unroll
    for (int i = 0; i < 8; ++i) {
        int p  = i * 256 + t;
        int r  = p >> 5;
        int js = p & 31;
        int j  = (js & 24) | ((js & 7) ^ (r & 7));
        const unsigned short* g = h3b + (size_t)(rowBase + r) * COMM + j * 8;
        void* d = (char*)H3 + (size_t)(i * 256 + w * 64) * 16;
        __builtin_amdgcn_global_load_lds(
            (const AS1 void*)g, (AS3 void*)d, 16, 0, 0);
    }

    float kl = 0.f;
    for (int c = 0; c < 4; ++c) {
        f32x4 am[4], av[4];
#pragma unroll
        for (int v = 0; v < 4; ++v) {
            am[v] = (f32x4){0.f, 0.f, 0.f, 0.f};
            av[v] = (f32x4){0.f, 0.f, 0.f, 0.f};
        }
        for (int ks = 0; ks < 4; ++ks) {
            __syncthreads();
#pragma unroll
            for (int i = 0; i < 2; ++i) {
                int p  = i * 256 + t;
                int n  = p >> 3;
                int js = p & 7;
                int j  = js ^ (n & 7);
                const unsigned short* gm =
                    Wmt + (size_t)(c * 64 + n) * COMM + ks * 64 + j * 8;
                const unsigned short* gv =
                    Wvt + (size_t)(c * 64 + n) * COMM + ks * 64 + j * 8;
                void* dm = (char*)Wm + (size_t)(i * 256 + w * 64) * 16;
                void* dv = (char*)Wv + (size_t)(i * 256 + w * 64) * 16;
                __builtin_amdgcn_global_load_lds(
                    (const AS1 void*)gm, (AS3 void*)dm, 16, 0, 0);
                __builtin_amdgcn_global_load_lds(
                    (const AS1 void*)gv, (AS3 void*)dv, 16, 0, 0);
            }
            __syncthreads();
#pragma unroll
            for (int kk = 0; kk < 2; ++kk) {
                int jwg = ks * 8 + kk * 4 + q;
                bf16x8 af = *(const bf16x8*)((char*)H3 +
                    (size_t)(m * 32 + ((jwg & 24) | ((jwg & 7) ^ (m & 7)))) * 16);
                int jw = kk * 4 + q;
#pragma unroll
                for (int v = 0; v < 4; ++v) {
                    int n = 16 * v + j16;
                    size_t pos = (size_t)(n * 8 + (jw ^ (n & 7))) * 16;
                    bf16x8 bm = *(const bf16x8*)((char*)Wm + pos);
                    bf16x8 bv = *(const bf16x8*)((char*)Wv + pos);
                    am[v] = __builtin_amdgcn_mfma_f32_16x16x32_bf16(af, bm, am[v], 0, 0, 0);
                    av[v] = __builtin_amdgcn_mfma_f32_16x16x32_bf16(af, bv, av[v], 0, 0, 0);
                }
            }
        }
#pragma unroll
        for (int v = 0; v < 4; ++v) {
            int col = c * 64 + 16 * v + j16;
            float bm_ = bmu[col];
            float bv_ = bvar[col];
#pragma unroll
            for (int rg = 0; rg < 4; ++rg) {
                int row = rowBase + 16 * w + q * 4 + rg;
                float mu = am[v][rg] + bm_;
                float lv = av[v][rg] + bv_;
                float e  = expf(0.5f * lv);
                float s  = mu + eps[(size_t)row * COMM + col] * e;
                sample [(size_t)row * COMM + col] = s;
                sampleq[(size_t)row * COMM + col] = (char)f2i8(s, SSCALE);
                kl += 1.f + lv - mu * mu - e * e;
            }
        }
    }
#pragma unroll
    for (int off = 32; off; off >>= 1) kl += __shfl_down(kl, off);
    __shared__ float wsum[4];
    if (l == 0) wsum[w] = kl;
    __syncthreads();
    if (t == 0)
        klpart[blockIdx.x] = wsum[0] + wsum[1] + wsum[2] + wsum[3];
}

// ---------------------------------------------------------------------------
// i8 MFMA distance + argmin. score = pnormS - 2*dot_i8 (scaled, same argmin).
// A (128 rows x 256 k i8 = 32 KB) resident; B double-buffered 2 x 8 KB.
// 48 KB LDS -> 3 blocks/CU. One barrier per 64-k slice; next slice's
// global_load_lds issued right after the barrier (m97-style pipelining).
// ---------------------------------------------------------------------------
#define SPLITS 4
#define SPAN   (NPROTO / SPLITS)   // 2048
#define NT     (SPAN / 128)        // 16 proto tiles per block

__global__ __launch_bounds__(256) void vq_argmin_i8(
    const char* __restrict__ sampleq,
    const char* __restrict__ protoq,
    const float* __restrict__ pnormS,
    float* __restrict__ minval,
    int* __restrict__ minidx)
{
    __shared__ __align__(16) char As[32768];
    __shared__ __align__(16) char Bs[2][8192];

    const int t   = threadIdx.x;
    const int w   = t >> 6;
    const int l   = t & 63;
    const int q   = l >> 4;
    const int j16 = l & 15;
    const int wrow = (w >> 1) * 64;
    const int wcol = (w & 1) * 64;
    const int rowBase = blockIdx.x * 128;
    const int tBase   = blockIdx.y * NT;    // proto tile index base

    // stage A: 2048 16B chunks, xor-16 swizzle (chunk jc of row r at jc^(r&15))
#pragma unroll
    for (int i = 0; i < 8; ++i) {
        int p  = i * 256 + t;
        int r  = p >> 4;
        int cs = p & 15;
        int j  = cs ^ (r & 15);
        const char* g = sampleq + (size_t)(rowBase + r) * COMM + j * 16;
        void* d = As + (size_t)(i * 256 + w * 64) * 16;
        __builtin_amdgcn_global_load_lds(
            (const AS1 void*)g, (AS3 void*)d, 16, 0, 0);
    }
    // stage B(tile 0, slice 0) into buf 0 (tiled layout: fully sequential)
    {
        const char* src = protoq + (size_t)tBase * 32768;
#pragma unroll
        for (int i = 0; i < 2; ++i) {
            int p = i * 256 + t;
            __builtin_amdgcn_global_load_lds(
                (const AS1 void*)(src + (size_t)p * 16),
                (AS3 void*)(Bs[0] + (size_t)(i * 256 + w * 64) * 16), 16, 0, 0);
        }
    }

    float bestv[16];
    int   besti[16];
#pragma unroll
    for (int s = 0; s < 16; ++s) { bestv[s] = FLT_MAX; besti[s] = 0; }

    int buf = 0;
    for (int pt = 0; pt < NT; ++pt) {
        i32x4 acc[4][4];
#pragma unroll
        for (int u = 0; u < 4; ++u)
#pragma unroll
            for (int v = 0; v < 4; ++v) acc[u][v] = (i32x4){0, 0, 0, 0};

        for (int ks = 0; ks < 4; ++ks) {
            __syncthreads();                 // Bs[buf] (and A on first pass) ready
            int nks = ks + 1, npt = pt;
            if (nks == 4) { nks = 0; ++npt; }
            if (npt < NT) {
                const char* src = protoq + ((size_t)(tBase + npt) * 16 + nks * 4) * 2048;
#pragma unroll
                for (int i = 0; i < 2; ++i) {
                    int p = i * 256 + t;
                    __builtin_amdgcn_global_load_lds(
                        (const AS1 void*)(src + (size_t)p * 16),
                        (AS3 void*)(Bs[buf ^ 1] + (size_t)(i * 256 + w * 64) * 16), 16, 0, 0);
                }
            }
            // compute K=64 slice: 4 A-frags + 4 B-frags -> 16 MFMAs
            i32x4 af[4], bfv[4];
            int jc = ks * 4 + q;
#pragma unroll
            for (int u = 0; u < 4; ++u) {
                int mm = wrow + 16 * u + j16;
                af[u] = *(const i32x4*)(As + (size_t)(mm * 16 + (jc ^ (mm & 15))) * 16);
            }
#pragma unroll
            for (int v = 0; v < 4; ++v) {
                int n = wcol + 16 * v + j16;
                bfv[v] = *(const i32x4*)(Bs[buf] + (size_t)(q * 128 + n) * 16);
            }
#pragma unroll
            for (int u = 0; u < 4; ++u)
#pragma unroll
                for (int v = 0; v < 4; ++v)
                    acc[u][v] = __builtin_amdgcn_mfma_i32_16x16x64_i8(
                        af[u], bfv[v], acc[u][v], 0, 0, 0);
            buf ^= 1;
        }
        // epilogue: running argmin (exact i32 dot -> fp32, |dot| < 2^24)
        int pTile = (tBase + pt) * 128;
#pragma unroll
        for (int v = 0; v < 4; ++v) {
            int col  = pTile + wcol + 16 * v + j16;
            float pn = pnormS[col];
#pragma unroll
            for (int u = 0; u < 4; ++u)
#pragma unroll
                for (int rg = 0; rg < 4; ++rg) {
                    float sc   = pn - 2.f * (float)acc[u][v][rg];
                    int   slot = u * 4 + rg;
                    if (sc < bestv[slot]) { bestv[slot] = sc; besti[slot] = col; }
                }
        }
    }
    // reduce across the 16 cols held by j16 lanes (same rows)
#pragma unroll
    for (int off = 1; off < 16; off <<= 1) {
#pragma unroll
        for (int s = 0; s < 16; ++s) {
            float ov = __shfl_xor(bestv[s], off);
            int   oi = __shfl_xor(besti[s], off);
            if (ov < bestv[s] || (ov == bestv[s] && oi < besti[s])) {
                bestv[s] = ov; besti[s] = oi;
            }
        }
    }
    // cross-wave (col halves) via LDS scratch
    __syncthreads();
    float* cv = (float*)Bs;
    int*   ci = ((int*)Bs) + 256;
    if (j16 == 0) {
#pragma unroll
        for (int u = 0; u < 4; ++u)
#pragma unroll
            for (int rg = 0; rg < 4; ++rg) {
                int row = wrow + 16 * u + 4 * q + rg;
                cv[(w & 1) * 128 + row] = bestv[u * 4 + rg];
                ci[(w & 1) * 128 + row] = besti[u * 4 + rg];
            }
    }
    __syncthreads();
    if (t < 128) {
        float v0 = cv[t];       int i0 = ci[t];
        float v1 = cv[128 + t]; int i1 = ci[128 + t];
        if (v1 < v0 || (v1 == v0 && i1 < i0)) { v0 = v1; i0 = i1; }
        minval[(size_t)blockIdx.y * B_SZ + rowBase + t] = v0;
        minidx[(size_t)blockIdx.y * B_SZ + rowBase + t] = i0;
    }
}

// ---------------------------------------------------------------------------
// Fused combine + gather + straight-through write + MSE partials.
// ---------------------------------------------------------------------------
__global__ __launch_bounds__(256) void gather_kernel(const float* __restrict__ sample,
                                                     const float* __restrict__ protos,
                                                     const float* __restrict__ minval,
                                                     const int* __restrict__ minidx,
                                                     float* __restrict__ out,
                                                     float* __restrict__ msepart)
{
    int t  = threadIdx.x;
    int rb = blockIdx.x * 8;
    __shared__ int sidx[8];
    if (t < 8) {
        int i = rb + t;
        float bv = minval[i];
        int   bi = minidx[i];
#pragma unroll
        for (int s = 1; s < SPLITS; ++s) {
            float v = minval[(size_t)s * B_SZ + i];
            int   j = minidx[(size_t)s * B_SZ + i];
            if (v < bv || (v == bv && j < bi)) { bv = v; bi = j; }
        }
        sidx[t] = bi;
    }
    __syncthreads();
    float part = 0.f;
#pragma unroll
    for (int u = 0; u < 8; ++u) {
        int i  = rb + u;
        int id = sidx[u];
        float qv = protos[(size_t)id * COMM + t];
        float s  = sample[(size_t)i * COMM + t];
        float d  = qv - s;
        out[(size_t)i * COMM + t] = s + d;
        part += d * d;
    }
#pragma unroll
    for (int off = 32; off; off >>= 1) part += __shfl_down(part, off);
    __shared__ float wsum[4];
    if ((t & 63) == 0) wsum[t >> 6] = part;
    __syncthreads();
    if (t == 0) msepart[blockIdx.x] = wsum[0] + wsum[1] + wsum[2] + wsum[3];
}

// ---------------------------------------------------------------------------
__global__ __launch_bounds__(256) void finalize_kernel(const float* __restrict__ klpart, int nkl,
                                                       const float* __restrict__ msepart, int nmse,
                                                       float* __restrict__ out)
{
    int t = threadIdx.x;
    double kl = 0.0, mse = 0.0;
    for (int i = t; i < nkl;  i += 256) kl  += (double)klpart[i];
    for (int i = t; i < nmse; i += 256) mse += (double)msepart[i];
#pragma unroll
    for (int off = 32; off; off >>= 1) {
        kl  += __shfl_down(kl, off);
        mse += __shfl_down(mse, off);
    }
    __shared__ double skl[4], smse[4];
    if ((t & 63) == 0) { skl[t >> 6] = kl; smse[t >> 6] = mse; }
    __syncthreads();
    if (t == 0) {
        double K  = skl[0] + skl[1] + skl[2] + skl[3];
        double M  = smse[0] + smse[1] + smse[2] + smse[3];
        double kld = -0.5 * K / (double)B_SZ;
        double vq  = 1.25 * M / ((double)B_SZ * (double)COMM);
        out[(size_t)B_SZ * COMM]     = (float)(kld + vq);
        out[(size_t)B_SZ * COMM + 1] = (float)kld;
    }
}

// ---------------------------------------------------------------------------
extern "C" void kernel_launch(void* const* d_in, const int* in_sizes, int n_in,
                              void* d_out, int out_size, void* d_ws, size_t ws_size,
                              hipStream_t stream)
{
    const float* x      = (const float*)d_in[0];
    const float* eps    = (const float*)d_in[1];
    const float* W_feat = (const float*)d_in[2];
    const float* b_feat = (const float*)d_in[3];
    const float* W0     = (const float*)d_in[4];
    const float* b0     = (const float*)d_in[5];
    const float* W1     = (const float*)d_in[6];
    const float* b1     = (const float*)d_in[7];
    const float* W_mu   = (const float*)d_in[8];
    const float* b_mu   = (const float*)d_in[9];
    const float* W_var  = (const float*)d_in[10];
    const float* b_var  = (const float*)d_in[11];
    const float* protos = (const float*)d_in[12];
    float* out = (float*)d_out;

    char* wsb = (char*)d_ws;
    size_t off = 0;
    auto alloc = [&](size_t bytes) -> void* {
        void* p = wsb + off;
        off = (off + bytes + 255) & ~(size_t)255;
        return p;
    };
    unsigned short* Wft     = (unsigned short*)alloc((size_t)IN_D * HID * 2);
    unsigned short* W0t     = (unsigned short*)alloc((size_t)HID * HID * 2);
    unsigned short* W1t     = (unsigned short*)alloc((size_t)HID * COMM * 2);
    unsigned short* Wmt     = (unsigned short*)alloc((size_t)COMM * COMM * 2);
    unsigned short* Wvt     = (unsigned short*)alloc((size_t)COMM * COMM * 2);
    unsigned short* h3b     = (unsigned short*)alloc((size_t)B_SZ * COMM * 2);
    float*          sample  = (float*)alloc((size_t)B_SZ * COMM * 4);
    char*           sampleq = (char*) alloc((size_t)B_SZ * COMM);
    char*           protoq  = (char*) alloc((size_t)NPROTO * COMM);
    float*          pnormS  = (float*)alloc((size_t)NPROTO * 4);
    float*          minval  = (float*)alloc((size_t)SPLITS * B_SZ * 4);
    int*            minidx  = (int*)  alloc((size_t)SPLITS * B_SZ * 4);
    float*          klpart  = (float*)alloc(512 * 4);
    float*          msepart = (float*)alloc(4096 * 4);

    prep_weights<<<848, 256, 0, stream>>>(W_feat, W0, W1, W_mu, W_var,
                                          Wft, W0t, W1t, Wmt, Wvt);
    pnorm_conv_kernel<<<NPROTO / 4, 256, 0, stream>>>(protos, pnormS, protoq);
    mlp_fused<<<B_SZ / 64, 256, 0, stream>>>(x, Wft, b_feat, W0t, b0, W1t, b1, h3b);
    head_mfma<<<B_SZ / 64, 256, 0, stream>>>(h3b, Wmt, b_mu, Wvt, b_var, eps,
                                             sample, sampleq, klpart);
    vq_argmin_i8<<<dim3(B_SZ / 128, SPLITS), 256, 0, stream>>>(sampleq, protoq, pnormS,
                                                               minval, minidx);
    gather_kernel<<<B_SZ / 8, 256, 0, stream>>>(sample, protos, minval, minidx,
                                                out, msepart);
    finalize_kernel<<<1, 256, 0, stream>>>(klpart, 512, msepart, 4096, out);
}

// Round 5
// 419.067 us; speedup vs baseline: 31.8011x; 1.0226x over previous
//
#include <hip/hip_runtime.h>
#include <cfloat>

#define B_SZ   32768
#define IN_D   1024
#define HID    64
#define COMM   256
#define NPROTO 8192

#define SSCALE 12.0f
#define PSCALE 1.0e6f

typedef __attribute__((ext_vector_type(8))) short bf16x8;
typedef __attribute__((ext_vector_type(4))) float f32x4;
typedef __attribute__((ext_vector_type(4))) int   i32x4;

#define AS1 __attribute__((address_space(1)))
#define AS3 __attribute__((address_space(3)))

__device__ __forceinline__ unsigned short f2bf(float f) {
    unsigned u = __float_as_uint(f);
    unsigned r = u + 0x7fff + ((u >> 16) & 1);   // round-to-nearest-even
    return (unsigned short)(r >> 16);
}

__device__ __forceinline__ int f2i8(float f, float scale) {
    float v = fminf(fmaxf(f * scale, -127.f), 127.f);
    return __float2int_rn(v);
}

// ---------------------------------------------------------------------------
// prep_all: blocks [0,848): weight transpose-convert fp32->bf16 W^T.
//           blocks [848,2896): protos -> int8 tiled + pnormS.
// ---------------------------------------------------------------------------
__global__ __launch_bounds__(256) void prep_all(
    const float* __restrict__ Wf,  const float* __restrict__ W0,
    const float* __restrict__ W1,  const float* __restrict__ Wmu,
    const float* __restrict__ Wvar, const float* __restrict__ protos,
    unsigned short* __restrict__ Wft, unsigned short* __restrict__ W0t,
    unsigned short* __restrict__ W1t, unsigned short* __restrict__ Wmt,
    unsigned short* __restrict__ Wvt,
    float* __restrict__ pnormS, char* __restrict__ protoq)
{
    int bid = blockIdx.x;
    if (bid < 848) {
        int gid = bid * 256 + threadIdx.x;
        const float* src; unsigned short* dst; int off, K, N;
        if (gid < 65536)       { src = Wf;  dst = Wft; off = gid;          K = 1024; N = 64;  }
        else if (gid < 69632)  { src = W0;  dst = W0t; off = gid - 65536;  K = 64;   N = 64;  }
        else if (gid < 86016)  { src = W1;  dst = W1t; off = gid - 69632;  K = 64;   N = 256; }
        else if (gid < 151552) { src = Wmu; dst = Wmt; off = gid - 86016;  K = 256;  N = 256; }
        else                   { src = Wvar;dst = Wvt; off = gid - 151552; K = 256;  N = 256; }
        int k = off / N, n = off % N;
        dst[(size_t)n * K + k] = f2bf(src[off]);
    } else {
        int g    = (bid - 848) * 256 + threadIdx.x;
        int p    = g >> 6;
        int lane = g & 63;
        float4 v = *(const float4*)&protos[(size_t)p * COMM + lane * 4];
        int b0 = f2i8(v.x, PSCALE) & 0xff;
        int b1 = f2i8(v.y, PSCALE) & 0xff;
        int b2 = f2i8(v.z, PSCALE) & 0xff;
        int b3 = f2i8(v.w, PSCALE) & 0xff;
        int pk = b0 | (b1 << 8) | (b2 << 16) | (b3 << 24);
        int T = p >> 7, jc = lane >> 2;
        *(int*)(protoq + ((size_t)(T * 16 + jc) * 128 + (p & 127)) * 16 + (lane & 3) * 4) = pk;
        float s = v.x * v.x + v.y * v.y + v.z * v.z + v.w * v.w;
#pragma unroll
        for (int off = 32; off; off >>= 1) s += __shfl_down(s, off);
        if (lane == 0) pnormS[p] = s * (SSCALE * PSCALE);
    }
}

// ---------------------------------------------------------------------------
// Fused MLP, 32 rows/block (grid 1024 -> 4 blocks/CU), 40 KB LDS, full dbuf.
// x staged as fp32 via global_load_lds, converted to bf16 at frag read.
// ---------------------------------------------------------------------------
__global__ __launch_bounds__(256, 4) void mlp_fused(
    const float* __restrict__ x,
    const unsigned short* __restrict__ Wft, const float* __restrict__ b_feat,
    const unsigned short* __restrict__ W0t, const float* __restrict__ b0,
    const unsigned short* __restrict__ W1t, const float* __restrict__ b1,
    unsigned short* __restrict__ h3b)
{
    __shared__ __align__(16) char lds[40960];
    char* Xs0 = lds;               // fp32 32r x 64k (8 KB)
    char* Xs1 = lds + 8192;
    char* Ws0 = lds + 16384;       // bf16 64n x 64k (8 KB)
    char* Ws1 = lds + 24576;
    char* H1  = lds + 32768;       // bf16 32r x 64c (4 KB)
    char* H2  = lds + 36864;       // 4 KB

    const int t   = threadIdx.x;
    const int w   = t >> 6;
    const int l   = t & 63;
    const int q   = l >> 4;
    const int j16 = l & 15;
    const int rh  = w >> 1;        // row half
    const int ch  = w & 1;         // col half
    const int rowBase = blockIdx.x * 32;
    const int m = rh * 16 + j16;   // local A row

    auto stageX = [&](int ks, char* dst) {
#pragma unroll
        for (int i = 0; i < 2; ++i) {
            int p  = i * 256 + t;
            int r  = p >> 4;
            int cs = p & 15;
            int j  = cs ^ (r & 15);                 // 16B chunk (4 fp32)
            const float* g = x + (size_t)(rowBase + r) * IN_D + ks * 64 + j * 4;
            void* d = dst + (size_t)(i * 256 + w * 64) * 16;
            __builtin_amdgcn_global_load_lds((const AS1 void*)g, (AS3 void*)d, 16, 0, 0);
        }
    };
    auto stageW = [&](const unsigned short* Wt, int ldk, int ks, char* dst) {
#pragma unroll
        for (int i = 0; i < 2; ++i) {
            int p  = i * 256 + t;
            int n  = p >> 3;
            int cs = p & 7;
            int j  = cs ^ (n & 7);                  // 16B chunk (8 bf16)
            const unsigned short* g = Wt + (size_t)n * ldk + ks * 64 + j * 8;
            void* d = dst + (size_t)(i * 256 + w * 64) * 16;
            __builtin_amdgcn_global_load_lds((const AS1 void*)g, (AS3 void*)d, 16, 0, 0);
        }
    };
    auto afragX = [&](const char* Xsb, int kk) -> bf16x8 {
        int jc = kk * 8 + q * 2;
        f32x4 a0 = *(const f32x4*)(Xsb + (size_t)(m * 16 + (jc ^ (m & 15))) * 16);
        f32x4 a1 = *(const f32x4*)(Xsb + (size_t)(m * 16 + ((jc + 1) ^ (m & 15))) * 16);
        bf16x8 o;
        o[0] = (short)f2bf(a0[0]); o[1] = (short)f2bf(a0[1]);
        o[2] = (short)f2bf(a0[2]); o[3] = (short)f2bf(a0[3]);
        o[4] = (short)f2bf(a1[0]); o[5] = (short)f2bf(a1[1]);
        o[6] = (short)f2bf(a1[2]); o[7] = (short)f2bf(a1[3]);
        return o;
    };
    auto bfrag = [&](const char* Wsb, int kk, int v) -> bf16x8 {
        int n  = ch * 32 + 16 * v + j16;
        int jc = kk * 4 + q;
        return *(const bf16x8*)(Wsb + (size_t)(n * 8 + (jc ^ (n & 7))) * 16);
    };
    auto afragH = [&](const char* Hs, int kk) -> bf16x8 {
        int jc = kk * 4 + q;
        return *(const bf16x8*)(Hs + (size_t)(m * 8 + (jc ^ (m & 7))) * 16);
    };

    // ================= stage 1: h1 = x @ Wf + bf (K=1024) ==================
    f32x4 acc1[2];
#pragma unroll
    for (int v = 0; v < 2; ++v) acc1[v] = (f32x4){0.f, 0.f, 0.f, 0.f};

    stageX(0, Xs0);
    stageW(Wft, IN_D, 0, Ws0);
    for (int ks = 0; ks < 16; ++ks) {
        int buf = ks & 1;
        __syncthreads();
        if (ks < 15) {
            stageX(ks + 1, buf ? Xs0 : Xs1);
            stageW(Wft, IN_D, ks + 1, buf ? Ws0 : Ws1);
        }
        const char* Xsb = buf ? Xs1 : Xs0;
        const char* Wsb = buf ? Ws1 : Ws0;
#pragma unroll
        for (int kk = 0; kk < 2; ++kk) {
            bf16x8 af = afragX(Xsb, kk);
#pragma unroll
            for (int v = 0; v < 2; ++v)
                acc1[v] = __builtin_amdgcn_mfma_f32_16x16x32_bf16(
                    af, bfrag(Wsb, kk, v), acc1[v], 0, 0, 0);
        }
    }
    // epilogue 1 -> H1 (no relu)
#pragma unroll
    for (int v = 0; v < 2; ++v) {
        int c = ch * 32 + 16 * v + j16;
        float bb = b_feat[c];
#pragma unroll
        for (int rg = 0; rg < 4; ++rg) {
            int r = rh * 16 + q * 4 + rg;
            float h = acc1[v][rg] + bb;
            *(short*)(H1 + (size_t)(r * 8 + ((c >> 3) ^ (r & 7))) * 16 + (c & 7) * 2)
                = (short)f2bf(h);
        }
    }
    stageW(W0t, 64, 0, Ws0);       // Ws0 free (last read was slice 14)
    __syncthreads();               // H1 + W0 ready; all stage-1 compute done

    // ================= stage 2: h2 = relu(h1 @ W0 + b0) ====================
    f32x4 acc2[2];
#pragma unroll
    for (int v = 0; v < 2; ++v) acc2[v] = (f32x4){0.f, 0.f, 0.f, 0.f};
#pragma unroll
    for (int kk = 0; kk < 2; ++kk) {
        bf16x8 af = afragH(H1, kk);
#pragma unroll
        for (int v = 0; v < 2; ++v)
            acc2[v] = __builtin_amdgcn_mfma_f32_16x16x32_bf16(
                af, bfrag(Ws0, kk, v), acc2[v], 0, 0, 0);
    }
#pragma unroll
    for (int v = 0; v < 2; ++v) {
        int c = ch * 32 + 16 * v + j16;
        float bb = b0[c];
#pragma unroll
        for (int rg = 0; rg < 4; ++rg) {
            int r = rh * 16 + q * 4 + rg;
            float h = fmaxf(acc2[v][rg] + bb, 0.f);
            *(short*)(H2 + (size_t)(r * 8 + ((c >> 3) ^ (r & 7))) * 16 + (c & 7) * 2)
                = (short)f2bf(h);
        }
    }
    stageW(W1t, 64, 0, Ws1);       // W1 chunk 0 (Ws1 free since stage-1 barrier)
    __syncthreads();               // H2 + W1c0 ready; Ws0 free

    // ================= stage 3: h3 = relu(h2 @ W1 + b1), 4 col chunks ======
    auto stage3 = [&](int c4, const char* Wsb) {
        f32x4 acc[2];
#pragma unroll
        for (int v = 0; v < 2; ++v) acc[v] = (f32x4){0.f, 0.f, 0.f, 0.f};
#pragma unroll
        for (int kk = 0; kk < 2; ++kk) {
            bf16x8 af = afragH(H2, kk);
#pragma unroll
            for (int v = 0; v < 2; ++v)
                acc[v] = __builtin_amdgcn_mfma_f32_16x16x32_bf16(
                    af, bfrag(Wsb, kk, v), acc[v], 0, 0, 0);
        }
#pragma unroll
        for (int v = 0; v < 2; ++v) {
            int col = c4 * 64 + ch * 32 + 16 * v + j16;
            float bb = b1[col];
#pragma unroll
            for (int rg = 0; rg < 4; ++rg) {
                int row = rowBase + rh * 16 + q * 4 + rg;
                float h = fmaxf(acc[v][rg] + bb, 0.f);
                h3b[(size_t)row * COMM + col] = f2bf(h);
            }
        }
    };
    stageW(W1t + (size_t)64 * 64, 64, 0, Ws0);    // c1 prefetch
    stage3(0, Ws1);
    __syncthreads();
    stageW(W1t + (size_t)128 * 64, 64, 0, Ws1);   // c2
    stage3(1, Ws0);
    __syncthreads();
    stageW(W1t + (size_t)192 * 64, 64, 0, Ws0);   // c3
    stage3(2, Ws1);
    __syncthreads();
    stage3(3, Ws0);
}

// ---------------------------------------------------------------------------
// Head, 32 rows/block (grid 1024), 32 KB LDS.
// ---------------------------------------------------------------------------
__global__ __launch_bounds__(256, 4) void head_mfma(
    const unsigned short* __restrict__ h3b,
    const unsigned short* __restrict__ Wmt, const float* __restrict__ bmu,
    const unsigned short* __restrict__ Wvt, const float* __restrict__ bvar,
    const float* __restrict__ eps,
    float* __restrict__ sample,
    char* __restrict__ sampleq,
    float* __restrict__ klpart)
{
    __shared__ __align__(16) char lds[32768];
    char* H3 = lds;                 // 16 KB: 32 r x 32 chunks, swizzled
    char* Wm = lds + 16384;         // 8 KB
    char* Wv = lds + 24576;         // 8 KB

    const int t   = threadIdx.x;
    const int w   = t >> 6;
    const int l   = t & 63;
    const int q   = l >> 4;
    const int j16 = l & 15;
    const int rh  = w >> 1;
    const int ch  = w & 1;
    const int rowBase = blockIdx.x * 32;
    const int m = rh * 16 + j16;

    // stage H3: 1024 chunks, 4/thread
#pragma unroll
    for (int i = 0; i < 4; ++i) {
        int p  = i * 256 + t;
        int r  = p >> 5;
        int js = p & 31;
        int j  = (js & 24) | ((js & 7) ^ (r & 7));
        const unsigned short* g = h3b + (size_t)(rowBase + r) * COMM + j * 8;
        void* d = H3 + (size_t)(i * 256 + w * 64) * 16;
        __builtin_amdgcn_global_load_lds((const AS1 void*)g, (AS3 void*)d, 16, 0, 0);
    }

    float kl = 0.f;
    for (int c = 0; c < 4; ++c) {
        f32x4 am[2], av[2];
#pragma unroll
        for (int v = 0; v < 2; ++v) {
            am[v] = (f32x4){0.f, 0.f, 0.f, 0.f};
            av[v] = (f32x4){0.f, 0.f, 0.f, 0.f};
        }
        for (int ks = 0; ks < 4; ++ks) {
            __syncthreads();      // prior compute done (and H3 ready first time)
#pragma unroll
            for (int i = 0; i < 2; ++i) {
                int p  = i * 256 + t;
                int n  = p >> 3;
                int js = p & 7;
                int j  = js ^ (n & 7);
                const unsigned short* gm =
                    Wmt + (size_t)(c * 64 + n) * COMM + ks * 64 + j * 8;
                const unsigned short* gv =
                    Wvt + (size_t)(c * 64 + n) * COMM + ks * 64 + j * 8;
                void* dm = Wm + (size_t)(i * 256 + w * 64) * 16;
                void* dv = Wv + (size_t)(i * 256 + w * 64) * 16;
                __builtin_amdgcn_global_load_lds((const AS1 void*)gm, (AS3 void*)dm, 16, 0, 0);
                __builtin_amdgcn_global_load_lds((const AS1 void*)gv, (AS3 void*)dv, 16, 0, 0);
            }
            __syncthreads();
#pragma unroll
            for (int kk = 0; kk < 2; ++kk) {
                int jwg = ks * 8 + kk * 4 + q;
                bf16x8 af = *(const bf16x8*)(H3 +
                    (size_t)(m * 32 + ((jwg & 24) | ((jwg & 7) ^ (m & 7)))) * 16);
                int jw = kk * 4 + q;
#pragma unroll
                for (int v = 0; v < 2; ++v) {
                    int n = ch * 32 + 16 * v + j16;
                    size_t pos = (size_t)(n * 8 + (jw ^ (n & 7))) * 16;
                    bf16x8 bm = *(const bf16x8*)(Wm + pos);
                    bf16x8 bv = *(const bf16x8*)(Wv + pos);
                    am[v] = __builtin_amdgcn_mfma_f32_16x16x32_bf16(af, bm, am[v], 0, 0, 0);
                    av[v] = __builtin_amdgcn_mfma_f32_16x16x32_bf16(af, bv, av[v], 0, 0, 0);
                }
            }
        }
#pragma unroll
        for (int v = 0; v < 2; ++v) {
            int col = c * 64 + ch * 32 + 16 * v + j16;
            float bm_ = bmu[col];
            float bv_ = bvar[col];
#pragma unroll
            for (int rg = 0; rg < 4; ++rg) {
                int row = rowBase + rh * 16 + q * 4 + rg;
                float mu = am[v][rg] + bm_;
                float lv = av[v][rg] + bv_;
                float e  = expf(0.5f * lv);
                float s  = mu + eps[(size_t)row * COMM + col] * e;
                sample [(size_t)row * COMM + col] = s;
                sampleq[(size_t)row * COMM + col] = (char)f2i8(s, SSCALE);
                kl += 1.f + lv - mu * mu - e * e;
            }
        }
    }
#pragma unroll
    for (int off = 32; off; off >>= 1) kl += __shfl_down(kl, off);
    __shared__ float wsum[4];
    if (l == 0) wsum[w] = kl;
    __syncthreads();
    if (t == 0)
        klpart[blockIdx.x] = wsum[0] + wsum[1] + wsum[2] + wsum[3];
}

// ---------------------------------------------------------------------------
// i8 MFMA distance + argmin, A-fragments hoisted into registers.
// LDS: A staging 32 KB (read once) + B dbuf 2x8 KB.
// ---------------------------------------------------------------------------
#define SPLITS 4
#define SPAN   (NPROTO / SPLITS)   // 2048
#define NT     (SPAN / 128)        // 16 proto tiles per block

__global__ __launch_bounds__(256, 2) void vq_argmin_i8(
    const char* __restrict__ sampleq,
    const char* __restrict__ protoq,
    const float* __restrict__ pnormS,
    float* __restrict__ minval,
    int* __restrict__ minidx)
{
    __shared__ __align__(16) char As[32768];
    __shared__ __align__(16) char Bs[2][8192];

    const int t   = threadIdx.x;
    const int w   = t >> 6;
    const int l   = t & 63;
    const int q   = l >> 4;
    const int j16 = l & 15;
    const int wrow = (w >> 1) * 64;
    const int wcol = (w & 1) * 64;
    const int rowBase = blockIdx.x * 128;
    const int tBase   = blockIdx.y * NT;

    // stage A: 2048 16B chunks, xor-16 swizzle
#pragma unroll
    for (int i = 0; i < 8; ++i) {
        int p  = i * 256 + t;
        int r  = p >> 4;
        int cs = p & 15;
        int j  = cs ^ (r & 15);
        const char* g = sampleq + (size_t)(rowBase + r) * COMM + j * 16;
        void* d = As + (size_t)(i * 256 + w * 64) * 16;
        __builtin_amdgcn_global_load_lds((const AS1 void*)g, (AS3 void*)d, 16, 0, 0);
    }
    // stage B(tile 0, slice 0) -> Bs[0]
    {
        const char* src = protoq + (size_t)tBase * 32768;
#pragma unroll
        for (int i = 0; i < 2; ++i) {
            int p = i * 256 + t;
            __builtin_amdgcn_global_load_lds(
                (const AS1 void*)(src + (size_t)p * 16),
                (AS3 void*)(Bs[0] + (size_t)(i * 256 + w * 64) * 16), 16, 0, 0);
        }
    }
    __syncthreads();

    // hoist all 16 A-frags into registers (zero A LDS reads in the loop)
    i32x4 af[4][4];
#pragma unroll
    for (int u = 0; u < 4; ++u)
#pragma unroll
        for (int ks = 0; ks < 4; ++ks) {
            int mm = wrow + 16 * u + j16;
            int jc = ks * 4 + q;
            af[u][ks] = *(const i32x4*)(As + (size_t)(mm * 16 + (jc ^ (mm & 15))) * 16);
        }

    float bestv[16];
    int   besti[16];
#pragma unroll
    for (int s = 0; s < 16; ++s) { bestv[s] = FLT_MAX; besti[s] = 0; }

    int buf = 0;
    for (int pt = 0; pt < NT; ++pt) {
        i32x4 acc[4][4];
#pragma unroll
        for (int u = 0; u < 4; ++u)
#pragma unroll
            for (int v = 0; v < 4; ++v) acc[u][v] = (i32x4){0, 0, 0, 0};

        for (int ks = 0; ks < 4; ++ks) {
            if (pt | ks) __syncthreads();     // Bs[buf] ready, prior reads done
            int nks = ks + 1, npt = pt;
            if (nks == 4) { nks = 0; ++npt; }
            if (npt < NT) {
                const char* src = protoq + ((size_t)(tBase + npt) * 16 + nks * 4) * 2048;
#pragma unroll
                for (int i = 0; i < 2; ++i) {
                    int p = i * 256 + t;
                    __builtin_amdgcn_global_load_lds(
                        (const AS1 void*)(src + (size_t)p * 16),
                        (AS3 void*)(Bs[buf ^ 1] + (size_t)(i * 256 + w * 64) * 16), 16, 0, 0);
                }
            }
            i32x4 bfv[4];
#pragma unroll
            for (int v = 0; v < 4; ++v) {
                int n = wcol + 16 * v + j16;
                bfv[v] = *(const i32x4*)(Bs[buf] + (size_t)(q * 128 + n) * 16);
            }
#pragma unroll
            for (int u = 0; u < 4; ++u)
#pragma unroll
                for (int v = 0; v < 4; ++v)
                    acc[u][v] = __builtin_amdgcn_mfma_i32_16x16x64_i8(
                        af[u][ks], bfv[v], acc[u][v], 0, 0, 0);
            buf ^= 1;
        }
        int pTile = (tBase + pt) * 128;
#pragma unroll
        for (int v = 0; v < 4; ++v) {
            int col  = pTile + wcol + 16 * v + j16;
            float pn = pnormS[col];
#pragma unroll
            for (int u = 0; u < 4; ++u)
#pragma unroll
                for (int rg = 0; rg < 4; ++rg) {
                    float sc   = pn - 2.f * (float)acc[u][v][rg];
                    int   slot = u * 4 + rg;
                    if (sc < bestv[slot]) { bestv[slot] = sc; besti[slot] = col; }
                }
        }
    }
    // reduce across the 16 col-lanes (same rows)
#pragma unroll
    for (int off = 1; off < 16; off <<= 1) {
#pragma unroll
        for (int s = 0; s < 16; ++s) {
            float ov = __shfl_xor(bestv[s], off);
            int   oi = __shfl_xor(besti[s], off);
            if (ov < bestv[s] || (ov == bestv[s] && oi < besti[s])) {
                bestv[s] = ov; besti[s] = oi;
            }
        }
    }
    // cross-wave (col halves) via LDS scratch
    __syncthreads();
    float* cv = (float*)Bs;
    int*   ci = ((int*)Bs) + 256;
    if (j16 == 0) {
#pragma unroll
        for (int u = 0; u < 4; ++u)
#pragma unroll
            for (int rg = 0; rg < 4; ++rg) {
                int row = wrow + 16 * u + 4 * q + rg;
                cv[(w & 1) * 128 + row] = bestv[u * 4 + rg];
                ci[(w & 1) * 128 + row] = besti[u * 4 + rg];
            }
    }
    __syncthreads();
    if (t < 128) {
        float v0 = cv[t];       int i0 = ci[t];
        float v1 = cv[128 + t]; int i1 = ci[128 + t];
        if (v1 < v0 || (v1 == v0 && i1 < i0)) { v0 = v1; i0 = i1; }
        minval[(size_t)blockIdx.y * B_SZ + rowBase + t] = v0;
        minidx[(size_t)blockIdx.y * B_SZ + rowBase + t] = i0;
    }
}

// ---------------------------------------------------------------------------
// Fused combine + gather + straight-through write + MSE partials.
// ---------------------------------------------------------------------------
__global__ __launch_bounds__(256) void gather_kernel(const float* __restrict__ sample,
                                                     const float* __restrict__ protos,
                                                     const float* __restrict__ minval,
                                                     const int* __restrict__ minidx,
                                                     float* __restrict__ out,
                                                     float* __restrict__ msepart)
{
    int t  = threadIdx.x;
    int rb = blockIdx.x * 8;
    __shared__ int sidx[8];
    if (t < 8) {
        int i = rb + t;
        float bv = minval[i];
        int   bi = minidx[i];
#pragma unroll
        for (int s = 1; s < SPLITS; ++s) {
            float v = minval[(size_t)s * B_SZ + i];
            int   j = minidx[(size_t)s * B_SZ + i];
            if (v < bv || (v == bv && j < bi)) { bv = v; bi = j; }
        }
        sidx[t] = bi;
    }
    __syncthreads();
    float part = 0.f;
#pragma unroll
    for (int u = 0; u < 8; ++u) {
        int i  = rb + u;
        int id = sidx[u];
        float qv = protos[(size_t)id * COMM + t];
        float s  = sample[(size_t)i * COMM + t];
        float d  = qv - s;
        out[(size_t)i * COMM + t] = s + d;
        part += d * d;
    }
#pragma unroll
    for (int off = 32; off; off >>= 1) part += __shfl_down(part, off);
    __shared__ float wsum[4];
    if ((t & 63) == 0) wsum[t >> 6] = part;
    __syncthreads();
    if (t == 0) msepart[blockIdx.x] = wsum[0] + wsum[1] + wsum[2] + wsum[3];
}

// ---------------------------------------------------------------------------
__global__ __launch_bounds__(256) void finalize_kernel(const float* __restrict__ klpart, int nkl,
                                                       const float* __restrict__ msepart, int nmse,
                                                       float* __restrict__ out)
{
    int t = threadIdx.x;
    double kl = 0.0, mse = 0.0;
    for (int i = t; i < nkl;  i += 256) kl  += (double)klpart[i];
    for (int i = t; i < nmse; i += 256) mse += (double)msepart[i];
#pragma unroll
    for (int off = 32; off; off >>= 1) {
        kl  += __shfl_down(kl, off);
        mse += __shfl_down(mse, off);
    }
    __shared__ double skl[4], smse[4];
    if ((t & 63) == 0) { skl[t >> 6] = kl; smse[t >> 6] = mse; }
    __syncthreads();
    if (t == 0) {
        double K  = skl[0] + skl[1] + skl[2] + skl[3];
        double M  = smse[0] + smse[1] + smse[2] + smse[3];
        double kld = -0.5 * K / (double)B_SZ;
        double vq  = 1.25 * M / ((double)B_SZ * (double)COMM);
        out[(size_t)B_SZ * COMM]     = (float)(kld + vq);
        out[(size_t)B_SZ * COMM + 1] = (float)kld;
    }
}

// ---------------------------------------------------------------------------
extern "C" void kernel_launch(void* const* d_in, const int* in_sizes, int n_in,
                              void* d_out, int out_size, void* d_ws, size_t ws_size,
                              hipStream_t stream)
{
    const float* x      = (const float*)d_in[0];
    const float* eps    = (const float*)d_in[1];
    const float* W_feat = (const float*)d_in[2];
    const float* b_feat = (const float*)d_in[3];
    const float* W0     = (const float*)d_in[4];
    const float* b0     = (const float*)d_in[5];
    const float* W1     = (const float*)d_in[6];
    const float* b1     = (const float*)d_in[7];
    const float* W_mu   = (const float*)d_in[8];
    const float* b_mu   = (const float*)d_in[9];
    const float* W_var  = (const float*)d_in[10];
    const float* b_var  = (const float*)d_in[11];
    const float* protos = (const float*)d_in[12];
    float* out = (float*)d_out;

    char* wsb = (char*)d_ws;
    size_t off = 0;
    auto alloc = [&](size_t bytes) -> void* {
        void* p = wsb + off;
        off = (off + bytes + 255) & ~(size_t)255;
        return p;
    };
    unsigned short* Wft     = (unsigned short*)alloc((size_t)IN_D * HID * 2);
    unsigned short* W0t     = (unsigned short*)alloc((size_t)HID * HID * 2);
    unsigned short* W1t     = (unsigned short*)alloc((size_t)HID * COMM * 2);
    unsigned short* Wmt     = (unsigned short*)alloc((size_t)COMM * COMM * 2);
    unsigned short* Wvt     = (unsigned short*)alloc((size_t)COMM * COMM * 2);
    unsigned short* h3b     = (unsigned short*)alloc((size_t)B_SZ * COMM * 2);
    float*          sample  = (float*)alloc((size_t)B_SZ * COMM * 4);
    char*           sampleq = (char*) alloc((size_t)B_SZ * COMM);
    char*           protoq  = (char*) alloc((size_t)NPROTO * COMM);
    float*          pnormS  = (float*)alloc((size_t)NPROTO * 4);
    float*          minval  = (float*)alloc((size_t)SPLITS * B_SZ * 4);
    int*            minidx  = (int*)  alloc((size_t)SPLITS * B_SZ * 4);
    float*          klpart  = (float*)alloc(1024 * 4);
    float*          msepart = (float*)alloc(4096 * 4);

    prep_all<<<2896, 256, 0, stream>>>(W_feat, W0, W1, W_mu, W_var, protos,
                                       Wft, W0t, W1t, Wmt, Wvt, pnormS, protoq);
    mlp_fused<<<B_SZ / 32, 256, 0, stream>>>(x, Wft, b_feat, W0t, b0, W1t, b1, h3b);
    head_mfma<<<B_SZ / 32, 256, 0, stream>>>(h3b, Wmt, b_mu, Wvt, b_var, eps,
                                             sample, sampleq, klpart);
    vq_argmin_i8<<<dim3(B_SZ / 128, SPLITS), 256, 0, stream>>>(sampleq, protoq, pnormS,
                                                               minval, minidx);
    gather_kernel<<<B_SZ / 8, 256, 0, stream>>>(sample, protos, minval, minidx,
                                                out, msepart);
    finalize_kernel<<<1, 256, 0, stream>>>(klpart, 1024, msepart, 4096, out);
}